// Round 10
// baseline (371.419 us; speedup 1.0000x reference)
//
#include <hip/hip_runtime.h>
#include <stdint.h>

#define DIM   512
#define QKD   128
#define HID   1024
#define HID2  2048
#define OUTD  8
#define BATCH 4
#define SEQ   4096
#define ROWS  (BATCH*SEQ)   // 16384
#define LN_EPS 1e-5f

typedef unsigned short u16;
typedef unsigned int   u32;
typedef __bf16 bf16x8 __attribute__((ext_vector_type(8)));
typedef float  f32x4  __attribute__((ext_vector_type(4)));

// ---------- helpers ----------
__device__ inline u16 f2bf(float f){
    uint32_t u = __builtin_bit_cast(uint32_t, f);
    u += 0x7FFFu + ((u >> 16) & 1u);   // RNE
    return (u16)(u >> 16);
}
__device__ inline float bf2f(u16 h){
    uint32_t u = ((uint32_t)h) << 16;
    return __builtin_bit_cast(float, u);
}
__device__ inline void split_bf16(float x, u16 &hi, u16 &lo){
    hi = f2bf(x);
    float r = x - bf2f(hi);
    lo = f2bf(r);
}
__device__ inline bf16x8 ld_frag(const u16* p){
    uint4 r = *reinterpret_cast<const uint4*>(p);
    return __builtin_bit_cast(bf16x8, r);
}
__device__ inline f32x4 mfma16(bf16x8 a, bf16x8 b, f32x4 c){
    return __builtin_amdgcn_mfma_f32_16x16x32_bf16(a, b, c, 0, 0, 0);
}
__device__ inline float silu(float x){ return x / (1.f + expf(-x)); }
// async global->LDS: PER-LANE global src addr, wave-uniform LDS base (+lane*16B)
__device__ inline void gload_lds16(const u16* g, u16* l){
    __builtin_amdgcn_global_load_lds(
        (const __attribute__((address_space(1))) u32*)g,
        (__attribute__((address_space(3))) u32*)l, 16, 0, 0);
}

// ---------- P: split + transpose weights ----------
__global__ void prep_split(const float* __restrict__ Wh, const float* __restrict__ Wqk,
                           u16* whth, u16* whtl, u16* wqkth, u16* wqktl){
    int tid = blockIdx.x*256 + threadIdx.x;
    const int NWH = HID2*DIM;            // 1048576
    if (tid < NWH){
        int k = tid & (DIM-1);
        int n = tid >> 9;
        float w = Wh[(size_t)k*HID2 + n];
        u16 h,l; split_bf16(w,h,l);
        whth[tid]=h; whtl[tid]=l;
    } else {
        int t2 = tid - NWH;
        if (t2 < QKD*DIM){
            int k = t2 & (DIM-1);
            int n = t2 >> 9;
            float w = Wqk[(size_t)k*QKD + n];
            u16 h,l; split_bf16(w,h,l);
            wqkth[t2]=h; wqktl[t2]=l;
        }
    }
}

// ---------- K1: layernorm -> bf16 ----------
__global__ __launch_bounds__(256) void ln_kernel(const float* __restrict__ x,
                                                 const float* __restrict__ g,
                                                 const float* __restrict__ b,
                                                 u16* nh){
    int wave = threadIdx.x >> 6, lane = threadIdx.x & 63;
    int row  = blockIdx.x*4 + wave;
    const float* xr = x + (size_t)row*DIM;
    float4 v0 = *(const float4*)(xr + lane*8);
    float4 v1 = *(const float4*)(xr + lane*8 + 4);
    float xs[8] = {v0.x,v0.y,v0.z,v0.w,v1.x,v1.y,v1.z,v1.w};
    float s = 0.f, q = 0.f;
    #pragma unroll
    for (int i=0;i<8;++i){ s += xs[i]; q += xs[i]*xs[i]; }
    #pragma unroll
    for (int m=1;m<64;m<<=1){ s += __shfl_xor(s,m,64); q += __shfl_xor(q,m,64); }
    float mean = s * (1.f/DIM);
    float var  = q * (1.f/DIM) - mean*mean;
    float rstd = rsqrtf(var + LN_EPS);
    float4 g0 = *(const float4*)(g + lane*8);
    float4 g1 = *(const float4*)(g + lane*8 + 4);
    float4 b0 = *(const float4*)(b + lane*8);
    float4 b1 = *(const float4*)(b + lane*8 + 4);
    float gs[8] = {g0.x,g0.y,g0.z,g0.w,g1.x,g1.y,g1.z,g1.w};
    float bs[8] = {b0.x,b0.y,b0.z,b0.w,b1.x,b1.y,b1.z,b1.w};
    u16 hh[8];
    #pragma unroll
    for (int i=0;i<8;++i){
        float nv = (xs[i]-mean)*rstd*gs[i] + bs[i];
        hh[i] = f2bf(nv);
    }
    size_t o = (size_t)row*DIM + lane*8;
    *(uint4*)(nh + o) = *(uint4*)hh;
}

// ---------- K2: hidden = silu(bf16(n) @ (Wh_hi+Wh_lo) + bh) -> v_f + gate ----------
// m97 structure: 3 tiles staged via global_load_lds (linear LDS), dbuf, 1 barrier/ks.
// grid 2048 linear, XCD swizzle: 2 n-panels per XCD (B tiles L2-resident).
__global__ __launch_bounds__(256,2) void gemm_h(
        const u16* __restrict__ nh,
        const u16* __restrict__ bth, const u16* __restrict__ btl,
        const float* __restrict__ bh,
        u16* v_f, float* gate){
    __shared__ __align__(16) u16 SA [2][128*32];
    __shared__ __align__(16) u16 SB0[2][128*32];
    __shared__ __align__(16) u16 SB1[2][128*32];
    const int bid = blockIdx.x;
    const int xcd = bid & 7, bx = bid >> 3;
    const int nb = xcd*2 + (bx >> 7);    // 0..15
    const int mb = bx & 127;             // 0..127
    const int n0 = nb*128, m0 = mb*128;
    const int w = threadIdx.x >> 6, lane = threadIdx.x & 63;
    const int wr = w >> 1, wc = w & 1;

    auto stage = [&](int ks, int p){
        #pragma unroll
        for (int c=0;c<2;++c){
            int row = w*32 + c*16 + (lane>>2);       // 0..127
            const u16* gA = nh  + (size_t)(m0+row)*DIM + ks*32 + (lane&3)*8;
            const u16* gB0= bth + (size_t)(n0+row)*DIM + ks*32 + (lane&3)*8;
            const u16* gB1= btl + (size_t)(n0+row)*DIM + ks*32 + (lane&3)*8;
            int off = w*1024 + c*512;                // u16 elems, wave-uniform
            gload_lds16(gA , &SA [p][off]);
            gload_lds16(gB0, &SB0[p][off]);
            gload_lds16(gB1, &SB1[p][off]);
        }
    };

    stage(0, 0);
    __syncthreads();

    f32x4 acc[4][4] = {};
    for (int ks=0; ks<16; ++ks){
        const int p = ks & 1;
        if (ks < 15) stage(ks+1, p^1);
        bf16x8 Ah[4];
        #pragma unroll
        for (int rf=0;rf<4;++rf)
            Ah[rf] = ld_frag(&SA[p][(wr*64 + rf*16 + (lane&15))*32 + (lane>>4)*8]);
        #pragma unroll
        for (int cf=0;cf<4;++cf){
            bf16x8 Bh = ld_frag(&SB0[p][(wc*64 + cf*16 + (lane&15))*32 + (lane>>4)*8]);
            bf16x8 Bl = ld_frag(&SB1[p][(wc*64 + cf*16 + (lane&15))*32 + (lane>>4)*8]);
            #pragma unroll
            for (int rf=0;rf<4;++rf){
                acc[rf][cf] = mfma16(Ah[rf], Bh, acc[rf][cf]);
                acc[rf][cf] = mfma16(Ah[rf], Bl, acc[rf][cf]);
            }
        }
        __syncthreads();
    }
    #pragma unroll
    for (int rf=0;rf<4;++rf){
        #pragma unroll
        for (int cf=0;cf<4;++cf){
            #pragma unroll
            for (int r=0;r<4;++r){
                int row = m0 + wr*64 + rf*16 + (lane>>4)*4 + r;
                int col = n0 + wc*64 + cf*16 + (lane&15);
                float h = acc[rf][cf][r] + bh[col];
                float s = silu(h);
                if (col < HID){
                    int b = row >> 12, i = row & (SEQ-1);
                    size_t o = (((size_t)b*128 + (i>>5))*64 + (col>>4))*512
                             + (size_t)((col&15) + (((i>>3)&3)<<4))*8 + (i&7);
                    v_f[o] = f2bf(s);
                } else {
                    gate[(size_t)row*HID + (col - HID)] = s;
                }
            }
        }
    }
}

// ---------- K3: Z = silu(bf16(n) @ (Wqk_hi+Wqk_lo) + bqk); q,k bf16 frag-major ----------
// M-tile 64 -> grid 256 (full GPU). q_f/k_f: [it][ks][512], lane=(row&15)+16*((col>>3)&3)
__global__ __launch_bounds__(256,2) void gemm_qk(
        const u16* __restrict__ nh,
        const u16* __restrict__ bth, const u16* __restrict__ btl,
        const float* __restrict__ bqk, const float* __restrict__ gamma,
        const float* __restrict__ beta,
        u16* q_f, u16* k_f){
    __shared__ __align__(16) u16 At[64][40];
    __shared__ __align__(16) u16 Bt[2][128][40];
    int m0 = blockIdx.x * 64;
    int wave = threadIdx.x>>6, lane = threadIdx.x&63;
    int wr = wave>>1, wc = wave&1;   // wave: 32q x 64n
    f32x4 acc[2][4] = {};
    for (int ks=0; ks<16; ++ks){
        {
            int row = threadIdx.x>>2, ch = threadIdx.x&3;   // 64 rows x 4 chunks
            *(uint4*)&At[row][ch*8] = *(const uint4*)(nh + (size_t)(m0+row)*DIM + ks*32 + ch*8);
        }
        #pragma unroll
        for (int r=0;r<2;++r){
            int idx = r*256 + threadIdx.x;
            int row = idx>>2, ch = idx&3;
            size_t gb = (size_t)row*DIM + ks*32 + ch*8;   // n0 = 0, N=128
            *(uint4*)&Bt[0][row][ch*8] = *(const uint4*)(bth + gb);
            *(uint4*)&Bt[1][row][ch*8] = *(const uint4*)(btl + gb);
        }
        __syncthreads();
        bf16x8 Ah[2];
        #pragma unroll
        for (int rf=0;rf<2;++rf)
            Ah[rf] = ld_frag(&At[wr*32 + rf*16 + (lane&15)][(lane>>4)*8]);
        #pragma unroll
        for (int cf=0;cf<4;++cf){
            bf16x8 Bh = ld_frag(&Bt[0][wc*64 + cf*16 + (lane&15)][(lane>>4)*8]);
            bf16x8 Bl = ld_frag(&Bt[1][wc*64 + cf*16 + (lane&15)][(lane>>4)*8]);
            #pragma unroll
            for (int rf=0;rf<2;++rf){
                acc[rf][cf] = mfma16(Ah[rf], Bh, acc[rf][cf]);
                acc[rf][cf] = mfma16(Ah[rf], Bl, acc[rf][cf]);
            }
        }
        __syncthreads();
    }
    #pragma unroll
    for (int rf=0;rf<2;++rf){
        #pragma unroll
        for (int cf=0;cf<4;++cf){
            #pragma unroll
            for (int r=0;r<4;++r){
                int row = m0 + wr*32 + rf*16 + (lane>>4)*4 + r;
                int col = wc*64 + cf*16 + (lane&15);
                float z = silu(acc[rf][cf][r] + bqk[col]);
                float qv = z*gamma[col]       + beta[col];
                float kv = z*gamma[QKD + col] + beta[QKD + col];
                size_t lane_e = (size_t)((row&15) + (((col>>3)&3)<<4))*8 + (col&7);
                size_t it4ks  = (size_t)(row>>4)*4 + (col>>5);
                q_f[it4ks*512 + lane_e] = f2bf(qv);
                k_f[it4ks*512 + lane_e] = f2bf(kv);
            }
        }
    }
}

// ---------- K4: fused squared-relu attention, software-pipelined by one kt ----------
// grid = 512 (2/CU), 512 threads, 8 waves. xcd=bid&7 -> (batch,dhalf); qt=bid>>3.
// QTILE=64, KV=64, d-slice 512/block. Q staged once (16KB); K via global_load_lds
// dbuf, prefetched TWO regions ahead of its read; A dbuf pitch 72; V direct
// global->reg, read exactly once.
// Region kt: prefetch K[kt+2] | QK[kt+1] | pack A[kt+1] | PV[kt] (A synced last
// barrier) | barrier.  QK[kt+1] and PV[kt] are INDEPENDENT -> mutual stall fill;
// barrier drain lands a full region after prefetch issue (latency fully hidden).
__global__ __launch_bounds__(512,4) void attn(
        const u16* __restrict__ q_f, const u16* __restrict__ k_f,
        const u16* __restrict__ v_f, float* gate){
    __shared__ __align__(16) u16 QL[8192];       // 64q x 128d frag-major
    __shared__ __align__(16) u16 KT[2][8192];    // dbuf: 64j x 128d frag-major
    __shared__ __align__(16) u16 AT[2][64*72];   // dbuf: A = relu(S)^2, pitch 72
    const int bid = blockIdx.x, xcd = bid & 7;
    const int batch = xcd >> 1, dhalf = xcd & 1, qt = bid >> 3;
    const int i0 = qt * 64;
    const int w = threadIdx.x >> 6, lane = threadIdx.x & 63;
    const int fr = w >> 1, fc = w & 1;    // QK: 16q strip x 32j half
    const int ds = w;                     // PV: 64d slice

    f32x4 acc[4][4] = {};   // 64q x 64d per wave
    bf16x8 vb0[4];

    auto stageK = [&](int kt, int p){
        size_t kbase = ((size_t)(batch*256 + kt*4))*2048;
        #pragma unroll
        for (int c=0;c<2;++c){
            int off = w*1024 + c*512;
            gload_lds16(k_f + kbase + off + lane*8, &KT[p][off]);
        }
    };
    auto qk_compute = [&](int p, f32x4* sacc){
        #pragma unroll
        for (int ks=0;ks<4;++ks){
            bf16x8 qa = ld_frag(&QL[fr*2048 + ks*512 + lane*8]);
            #pragma unroll
            for (int t=0;t<2;++t){
                bf16x8 kb = ld_frag(&KT[p][(fc*2 + t)*2048 + ks*512 + lane*8]);
                sacc[t] = mfma16(qa, kb, sacc[t]);
            }
        }
    };
    auto pack_A = [&](int p, f32x4* sacc){
        u16* Ab = AT[p];
        #pragma unroll
        for (int t=0;t<2;++t){
            #pragma unroll
            for (int r=0;r<4;++r){
                float s = sacc[t][r];
                s = s > 0.f ? s*s : 0.f;
                int q = fr*16 + (lane>>4)*4 + r;
                int j = fc*32 + t*16 + (lane&15);
                Ab[q*72 + j] = f2bf(s);
            }
        }
    };
    auto loadV = [&](int kt, int kk, bf16x8* vb){
        #pragma unroll
        for (int dc=0;dc<4;++dc)
            vb[dc] = ld_frag(v_f + (((size_t)(batch*128 + kt*2 + kk))*64
                              + dhalf*32 + ds*4 + dc)*512 + lane*8);
    };
    auto pv = [&](int p, int kk, bf16x8* vb){
        #pragma unroll
        for (int qr=0;qr<4;++qr){
            bf16x8 af = ld_frag(&AT[p][(qr*16 + (lane&15))*72 + kk*32 + (lane>>4)*8]);
            #pragma unroll
            for (int dc=0;dc<4;++dc)
                acc[qr][dc] = mfma16(af, vb[dc], acc[qr][dc]);
        }
    };

    // ---- prologue: stage Q + K0; region -1 computes A[0], prefetches K1 ----
    {
        size_t qbase = ((size_t)(batch*256 + qt*4))*2048;
        #pragma unroll
        for (int c=0;c<2;++c){
            int off = w*1024 + c*512;
            gload_lds16(q_f + qbase + off + lane*8, &QL[off]);
        }
        stageK(0, 0);
    }
    __syncthreads();
    {
        f32x4 sacc[2] = {};
        qk_compute(0, sacc);
        pack_A(0, sacc);
        stageK(1, 1);
    }
    __syncthreads();
    loadV(0, 0, vb0);

    // ---- main: region kt does QK[kt+1] + PV[kt] ----
    for (int kt=0; kt<63; ++kt){
        if (kt < 62) stageK(kt+2, kt&1);
        f32x4 sacc[2] = {};
        __builtin_amdgcn_s_setprio(1);
        qk_compute((kt+1)&1, sacc);
        __builtin_amdgcn_s_setprio(0);
        pack_A((kt+1)&1, sacc);
        __builtin_amdgcn_s_setprio(1);
        pv(kt&1, 0, vb0);
        __builtin_amdgcn_s_setprio(0);
        bf16x8 vb1[4];
        loadV(kt, 1, vb1);
        __builtin_amdgcn_s_setprio(1);
        pv(kt&1, 1, vb1);
        __builtin_amdgcn_s_setprio(0);
        __syncthreads();   // A[kt+1] visible; K[kt+2] drained (issued full region ago)
        loadV(kt+1, 0, vb0);
    }
    // ---- epilogue: PV[63] ----
    pv(1, 0, vb0);
    {
        bf16x8 vb1[4];
        loadV(63, 1, vb1);
        pv(1, 1, vb1);
    }
    // ---- epilogue: gate <- V * gate * 2^-24 ----
    #pragma unroll
    for (int qr=0; qr<4; ++qr){
        #pragma unroll
        for (int dc=0; dc<4; ++dc){
            #pragma unroll
            for (int r=0; r<4; ++r){
                int i = i0 + qr*16 + (lane>>4)*4 + r;
                int d = dhalf*512 + ds*64 + dc*16 + (lane&15);
                size_t go = ((size_t)(batch*SEQ + i))*HID + d;
                float g = gate[go];
                gate[go] = acc[qr][dc][r] * g * 0x1p-24f;
            }
        }
    }
}

// ---------- K5: out = Vg @ Wo + bo ----------
__global__ __launch_bounds__(256) void wo_kernel(const float* __restrict__ vg,
                                                 const float* __restrict__ Wo,
                                                 const float* __restrict__ bo,
                                                 float* out){
    int wave = threadIdx.x>>6, lane = threadIdx.x&63;
    int row  = blockIdx.x*4 + wave;
    const float* vr = vg + (size_t)row*HID;
    float po[8] = {};
    #pragma unroll
    for (int c=0;c<4;++c){
        float4 v = *(const float4*)(vr + c*256 + lane*4);
        float vv[4] = {v.x, v.y, v.z, v.w};
        #pragma unroll
        for (int e=0;e<4;++e){
            int col = c*256 + lane*4 + e;
            float4 w0 = *(const float4*)(Wo + (size_t)col*8);
            float4 w1 = *(const float4*)(Wo + (size_t)col*8 + 4);
            po[0] += vv[e]*w0.x; po[1] += vv[e]*w0.y; po[2] += vv[e]*w0.z; po[3] += vv[e]*w0.w;
            po[4] += vv[e]*w1.x; po[5] += vv[e]*w1.y; po[6] += vv[e]*w1.z; po[7] += vv[e]*w1.w;
        }
    }
    #pragma unroll
    for (int m=1;m<64;m<<=1){
        #pragma unroll
        for (int o=0;o<8;++o) po[o] += __shfl_xor(po[o], m, 64);
    }
    if (lane == 0){
        #pragma unroll
        for (int o=0;o<8;++o) out[(size_t)row*8 + o] = po[o] + bo[o];
    }
}

// ---------- launch ----------
extern "C" void kernel_launch(void* const* d_in, const int* in_sizes, int n_in,
                              void* d_out, int out_size, void* d_ws, size_t ws_size,
                              hipStream_t stream){
    const float* x    = (const float*)d_in[0];
    const float* ln_g = (const float*)d_in[1];
    const float* ln_b = (const float*)d_in[2];
    const float* Wh   = (const float*)d_in[3];
    const float* bh   = (const float*)d_in[4];
    const float* Wqk  = (const float*)d_in[5];
    const float* bqk  = (const float*)d_in[6];
    const float* gamma= (const float*)d_in[7];
    const float* beta = (const float*)d_in[8];
    const float* Wo   = (const float*)d_in[9];
    const float* bo   = (const float*)d_in[10];
    float* out = (float*)d_out;

    char* w = (char*)d_ws;
    auto alloc = [&](size_t bytes)->char*{
        char* p = w; w += (bytes + 255) & ~(size_t)255; return p;
    };
    u16* nh    = (u16*)alloc((size_t)ROWS*DIM*2);
    u16* whth  = (u16*)alloc((size_t)HID2*DIM*2);
    u16* whtl  = (u16*)alloc((size_t)HID2*DIM*2);
    u16* wqkth = (u16*)alloc((size_t)QKD*DIM*2);
    u16* wqktl = (u16*)alloc((size_t)QKD*DIM*2);
    u16* q_f   = (u16*)alloc((size_t)ROWS*QKD*2);      // bf16, fragment-major
    u16* k_f   = (u16*)alloc((size_t)ROWS*QKD*2);      // bf16, fragment-major
    u16* v_f   = (u16*)alloc((size_t)BATCH*HID*SEQ*2); // bf16, fragment-major
    float* gate= (float*)alloc((size_t)ROWS*HID*4);

    prep_split<<<(HID2*DIM + QKD*DIM)/256, 256, 0, stream>>>(Wh, Wqk, whth, whtl, wqkth, wqktl);
    ln_kernel<<<ROWS/4, 256, 0, stream>>>(x, ln_g, ln_b, nh);
    gemm_h<<<2048, 256, 0, stream>>>(nh, whth, whtl, bh, v_f, gate);
    gemm_qk<<<ROWS/64, 256, 0, stream>>>(nh, wqkth, wqktl, bqk, gamma, beta, q_f, k_f);
    attn<<<512, 512, 0, stream>>>(q_f, k_f, v_f, gate);
    wo_kernel<<<ROWS/4, 256, 0, stream>>>(gate, Wo, bo, out);
}

// Round 11
// 343.173 us; speedup vs baseline: 1.0823x; 1.0823x over previous
//
#include <hip/hip_runtime.h>
#include <stdint.h>

#define DIM   512
#define QKD   128
#define HID   1024
#define HID2  2048
#define OUTD  8
#define BATCH 4
#define SEQ   4096
#define ROWS  (BATCH*SEQ)   // 16384
#define LN_EPS 1e-5f

typedef unsigned short u16;
typedef unsigned int   u32;
typedef __bf16 bf16x8 __attribute__((ext_vector_type(8)));
typedef float  f32x4  __attribute__((ext_vector_type(4)));

// ---------- helpers ----------
__device__ inline u16 f2bf(float f){
    uint32_t u = __builtin_bit_cast(uint32_t, f);
    u += 0x7FFFu + ((u >> 16) & 1u);   // RNE
    return (u16)(u >> 16);
}
__device__ inline float bf2f(u16 h){
    uint32_t u = ((uint32_t)h) << 16;
    return __builtin_bit_cast(float, u);
}
__device__ inline void split_bf16(float x, u16 &hi, u16 &lo){
    hi = f2bf(x);
    float r = x - bf2f(hi);
    lo = f2bf(r);
}
__device__ inline bf16x8 ld_frag(const u16* p){
    uint4 r = *reinterpret_cast<const uint4*>(p);
    return __builtin_bit_cast(bf16x8, r);
}
__device__ inline f32x4 mfma16(bf16x8 a, bf16x8 b, f32x4 c){
    return __builtin_amdgcn_mfma_f32_16x16x32_bf16(a, b, c, 0, 0, 0);
}
__device__ inline float silu(float x){ return x / (1.f + expf(-x)); }
// async global->LDS: PER-LANE global src addr, wave-uniform LDS base (+lane*16B)
__device__ inline void gload_lds16(const u16* g, u16* l){
    __builtin_amdgcn_global_load_lds(
        (const __attribute__((address_space(1))) u32*)g,
        (__attribute__((address_space(3))) u32*)l, 16, 0, 0);
}

// ---------- P: split/quantize weights ----------
// Wh -> plain bf16 (transposed); Wqk -> split hi/lo (transposed)
__global__ void prep_split(const float* __restrict__ Wh, const float* __restrict__ Wqk,
                           u16* whth, u16* wqkth, u16* wqktl){
    int tid = blockIdx.x*256 + threadIdx.x;
    const int NWH = HID2*DIM;            // 1048576
    if (tid < NWH){
        int k = tid & (DIM-1);
        int n = tid >> 9;
        whth[tid] = f2bf(Wh[(size_t)k*HID2 + n]);
    } else {
        int t2 = tid - NWH;
        if (t2 < QKD*DIM){
            int k = t2 & (DIM-1);
            int n = t2 >> 9;
            float w = Wqk[(size_t)k*QKD + n];
            u16 h,l; split_bf16(w,h,l);
            wqkth[t2]=h; wqktl[t2]=l;
        }
    }
}

// ---------- K1: layernorm -> bf16 ----------
__global__ __launch_bounds__(256) void ln_kernel(const float* __restrict__ x,
                                                 const float* __restrict__ g,
                                                 const float* __restrict__ b,
                                                 u16* nh){
    int wave = threadIdx.x >> 6, lane = threadIdx.x & 63;
    int row  = blockIdx.x*4 + wave;
    const float* xr = x + (size_t)row*DIM;
    float4 v0 = *(const float4*)(xr + lane*8);
    float4 v1 = *(const float4*)(xr + lane*8 + 4);
    float xs[8] = {v0.x,v0.y,v0.z,v0.w,v1.x,v1.y,v1.z,v1.w};
    float s = 0.f, q = 0.f;
    #pragma unroll
    for (int i=0;i<8;++i){ s += xs[i]; q += xs[i]*xs[i]; }
    #pragma unroll
    for (int m=1;m<64;m<<=1){ s += __shfl_xor(s,m,64); q += __shfl_xor(q,m,64); }
    float mean = s * (1.f/DIM);
    float var  = q * (1.f/DIM) - mean*mean;
    float rstd = rsqrtf(var + LN_EPS);
    float4 g0 = *(const float4*)(g + lane*8);
    float4 g1 = *(const float4*)(g + lane*8 + 4);
    float4 b0 = *(const float4*)(b + lane*8);
    float4 b1 = *(const float4*)(b + lane*8 + 4);
    float gs[8] = {g0.x,g0.y,g0.z,g0.w,g1.x,g1.y,g1.z,g1.w};
    float bs[8] = {b0.x,b0.y,b0.z,b0.w,b1.x,b1.y,b1.z,b1.w};
    u16 hh[8];
    #pragma unroll
    for (int i=0;i<8;++i){
        float nv = (xs[i]-mean)*rstd*gs[i] + bs[i];
        hh[i] = f2bf(nv);
    }
    size_t o = (size_t)row*DIM + lane*8;
    *(uint4*)(nh + o) = *(uint4*)hh;
}

// ---------- K2: hidden = silu(bf16(n) @ bf16(Wh) + bh) -> v_f + gate ----------
// m97 structure, ONE term: 2 tiles staged via global_load_lds, dbuf, 1 barrier/ks.
// grid 2048 linear, XCD swizzle: 2 n-panels per XCD (B tiles L2-resident).
__global__ __launch_bounds__(256,2) void gemm_h(
        const u16* __restrict__ nh,
        const u16* __restrict__ bth,
        const float* __restrict__ bh,
        u16* v_f, float* gate){
    __shared__ __align__(16) u16 SA[2][128*32];
    __shared__ __align__(16) u16 SB[2][128*32];
    const int bid = blockIdx.x;
    const int xcd = bid & 7, bx = bid >> 3;
    const int nb = xcd*2 + (bx >> 7);    // 0..15
    const int mb = bx & 127;             // 0..127
    const int n0 = nb*128, m0 = mb*128;
    const int w = threadIdx.x >> 6, lane = threadIdx.x & 63;
    const int wr = w >> 1, wc = w & 1;

    auto stage = [&](int ks, int p){
        #pragma unroll
        for (int c=0;c<2;++c){
            int row = w*32 + c*16 + (lane>>2);       // 0..127
            const u16* gA = nh  + (size_t)(m0+row)*DIM + ks*32 + (lane&3)*8;
            const u16* gB = bth + (size_t)(n0+row)*DIM + ks*32 + (lane&3)*8;
            int off = w*1024 + c*512;                // u16 elems, wave-uniform
            gload_lds16(gA, &SA[p][off]);
            gload_lds16(gB, &SB[p][off]);
        }
    };

    stage(0, 0);
    __syncthreads();

    f32x4 acc[4][4] = {};
    for (int ks=0; ks<16; ++ks){
        const int p = ks & 1;
        if (ks < 15) stage(ks+1, p^1);
        bf16x8 Ah[4];
        #pragma unroll
        for (int rf=0;rf<4;++rf)
            Ah[rf] = ld_frag(&SA[p][(wr*64 + rf*16 + (lane&15))*32 + (lane>>4)*8]);
        #pragma unroll
        for (int cf=0;cf<4;++cf){
            bf16x8 Bh = ld_frag(&SB[p][(wc*64 + cf*16 + (lane&15))*32 + (lane>>4)*8]);
            #pragma unroll
            for (int rf=0;rf<4;++rf)
                acc[rf][cf] = mfma16(Ah[rf], Bh, acc[rf][cf]);
        }
        __syncthreads();
    }
    #pragma unroll
    for (int rf=0;rf<4;++rf){
        #pragma unroll
        for (int cf=0;cf<4;++cf){
            #pragma unroll
            for (int r=0;r<4;++r){
                int row = m0 + wr*64 + rf*16 + (lane>>4)*4 + r;
                int col = n0 + wc*64 + cf*16 + (lane&15);
                float h = acc[rf][cf][r] + bh[col];
                float s = silu(h);
                if (col < HID){
                    int b = row >> 12, i = row & (SEQ-1);
                    size_t o = (((size_t)b*128 + (i>>5))*64 + (col>>4))*512
                             + (size_t)((col&15) + (((i>>3)&3)<<4))*8 + (i&7);
                    v_f[o] = f2bf(s);
                } else {
                    gate[(size_t)row*HID + (col - HID)] = s;
                }
            }
        }
    }
}

// ---------- K3: Z = silu(bf16(n) @ (Wqk_hi+Wqk_lo) + bqk); q,k bf16 frag-major ----------
// M-tile 64 -> grid 256 (full GPU). q_f/k_f: [it][ks][512], lane=(row&15)+16*((col>>3)&3)
__global__ __launch_bounds__(256,2) void gemm_qk(
        const u16* __restrict__ nh,
        const u16* __restrict__ bth, const u16* __restrict__ btl,
        const float* __restrict__ bqk, const float* __restrict__ gamma,
        const float* __restrict__ beta,
        u16* q_f, u16* k_f){
    __shared__ __align__(16) u16 At[64][40];
    __shared__ __align__(16) u16 Bt[2][128][40];
    int m0 = blockIdx.x * 64;
    int wave = threadIdx.x>>6, lane = threadIdx.x&63;
    int wr = wave>>1, wc = wave&1;   // wave: 32q x 64n
    f32x4 acc[2][4] = {};
    for (int ks=0; ks<16; ++ks){
        {
            int row = threadIdx.x>>2, ch = threadIdx.x&3;   // 64 rows x 4 chunks
            *(uint4*)&At[row][ch*8] = *(const uint4*)(nh + (size_t)(m0+row)*DIM + ks*32 + ch*8);
        }
        #pragma unroll
        for (int r=0;r<2;++r){
            int idx = r*256 + threadIdx.x;
            int row = idx>>2, ch = idx&3;
            size_t gb = (size_t)row*DIM + ks*32 + ch*8;   // n0 = 0, N=128
            *(uint4*)&Bt[0][row][ch*8] = *(const uint4*)(bth + gb);
            *(uint4*)&Bt[1][row][ch*8] = *(const uint4*)(btl + gb);
        }
        __syncthreads();
        bf16x8 Ah[2];
        #pragma unroll
        for (int rf=0;rf<2;++rf)
            Ah[rf] = ld_frag(&At[wr*32 + rf*16 + (lane&15)][(lane>>4)*8]);
        #pragma unroll
        for (int cf=0;cf<4;++cf){
            bf16x8 Bh = ld_frag(&Bt[0][wc*64 + cf*16 + (lane&15)][(lane>>4)*8]);
            bf16x8 Bl = ld_frag(&Bt[1][wc*64 + cf*16 + (lane&15)][(lane>>4)*8]);
            #pragma unroll
            for (int rf=0;rf<2;++rf){
                acc[rf][cf] = mfma16(Ah[rf], Bh, acc[rf][cf]);
                acc[rf][cf] = mfma16(Ah[rf], Bl, acc[rf][cf]);
            }
        }
        __syncthreads();
    }
    #pragma unroll
    for (int rf=0;rf<2;++rf){
        #pragma unroll
        for (int cf=0;cf<4;++cf){
            #pragma unroll
            for (int r=0;r<4;++r){
                int row = m0 + wr*32 + rf*16 + (lane>>4)*4 + r;
                int col = wc*64 + cf*16 + (lane&15);
                float z = silu(acc[rf][cf][r] + bqk[col]);
                float qv = z*gamma[col]       + beta[col];
                float kv = z*gamma[QKD + col] + beta[QKD + col];
                size_t lane_e = (size_t)((row&15) + (((col>>3)&3)<<4))*8 + (col&7);
                size_t it4ks  = (size_t)(row>>4)*4 + (col>>5);
                q_f[it4ks*512 + lane_e] = f2bf(qv);
                k_f[it4ks*512 + lane_e] = f2bf(kv);
            }
        }
    }
}

// ---------- K4: fused squared-relu attention (round-9 schedule, known-good) ----------
// grid = 512 blocks (2/CU), 512 threads, 8 waves. xcd=bid&7 -> (batch,dhalf);
// qt=bid>>3 (0..63), QTILE=64, KV=64, d-slice 512/block.
// Q staged once in LDS (16KB). K via global_load_lds dbuf (2x16KB), prefetch 1 ahead.
// QK: wave = (fr: 16q strip, fc: 32j half). PV: wave = ds (64d slice) -> V read
// exactly once, direct global->reg. A via LDS pitch 72, dbuf. ONE barrier per kt;
// the second CU-resident block fills barrier stalls.
__global__ __launch_bounds__(512,4) void attn(
        const u16* __restrict__ q_f, const u16* __restrict__ k_f,
        const u16* __restrict__ v_f, float* gate){
    __shared__ __align__(16) u16 QL[8192];       // 64q x 128d frag-major
    __shared__ __align__(16) u16 KT[2][8192];    // dbuf: 64j x 128d frag-major
    __shared__ __align__(16) u16 AT[2][64*72];   // dbuf: A = relu(S)^2, pitch 72
    const int bid = blockIdx.x, xcd = bid & 7;
    const int batch = xcd >> 1, dhalf = xcd & 1, qt = bid >> 3;
    const int i0 = qt * 64;
    const int w = threadIdx.x >> 6, lane = threadIdx.x & 63;
    const int fr = w >> 1, fc = w & 1;    // QK: 16q strip x 32j half
    const int ds = w;                     // PV: 64d slice

    // ---- stage Q once + K(0), async ----
    {
        size_t qbase = ((size_t)(batch*256 + qt*4))*2048;
        size_t kbase = ((size_t)(batch*256 + 0*4))*2048;
        #pragma unroll
        for (int c=0;c<2;++c){
            int off = w*1024 + c*512;
            gload_lds16(q_f + qbase + off + lane*8, &QL[off]);
            gload_lds16(k_f + kbase + off + lane*8, &KT[0][off]);
        }
    }
    __syncthreads();

    f32x4 acc[4][4] = {};   // 64q x 64d per wave
    for (int kt=0; kt<64; ++kt){
        const int p = kt & 1;
        // prefetch K(kt+1) -> other buffer (drains at this kt's barrier)
        {
            size_t kbase = ((size_t)(batch*256 + (((kt+1)&63))*4))*2048;
            #pragma unroll
            for (int c=0;c<2;++c){
                int off = w*1024 + c*512;
                gload_lds16(k_f + kbase + off + lane*8, &KT[p^1][off]);
            }
        }
        // V kk0 frags (consumed after barrier; latency covered by QK+pack)
        bf16x8 vb0[4];
        #pragma unroll
        for (int dc=0;dc<4;++dc)
            vb0[dc] = ld_frag(v_f + (((size_t)(batch*128 + kt*2))*64
                              + dhalf*32 + ds*4 + dc)*512 + lane*8);
        // ---- QK: S = q.k^T, wave does 16q x 32j ----
        f32x4 sacc[2] = {};
        #pragma unroll
        for (int ks=0;ks<4;++ks){
            bf16x8 qa = ld_frag(&QL[fr*2048 + ks*512 + lane*8]);
            #pragma unroll
            for (int t=0;t<2;++t){
                bf16x8 kb = ld_frag(&KT[p][(fc*2 + t)*2048 + ks*512 + lane*8]);
                sacc[t] = mfma16(qa, kb, sacc[t]);
            }
        }
        // ---- A = bf16(relu(S)^2) -> LDS (pitch 72, dbuf) ----
        u16* Ab = AT[p];
        #pragma unroll
        for (int t=0;t<2;++t){
            #pragma unroll
            for (int r=0;r<4;++r){
                float s = sacc[t][r];
                s = s > 0.f ? s*s : 0.f;
                int q = fr*16 + (lane>>4)*4 + r;
                int j = fc*32 + t*16 + (lane&15);
                Ab[q*72 + j] = f2bf(s);
            }
        }
        __syncthreads();   // A visible; K(kt+1) + vb0 drained
        // ---- PV kk0 ----
        #pragma unroll
        for (int qr=0;qr<4;++qr){
            bf16x8 af = ld_frag(&Ab[(qr*16 + (lane&15))*72 + (lane>>4)*8]);
            #pragma unroll
            for (int dc=0;dc<4;++dc)
                acc[qr][dc] = mfma16(af, vb0[dc], acc[qr][dc]);
        }
        // ---- V kk1 ----
        bf16x8 vb1[4];
        #pragma unroll
        for (int dc=0;dc<4;++dc)
            vb1[dc] = ld_frag(v_f + (((size_t)(batch*128 + kt*2 + 1))*64
                              + dhalf*32 + ds*4 + dc)*512 + lane*8);
        // ---- PV kk1 ----
        #pragma unroll
        for (int qr=0;qr<4;++qr){
            bf16x8 af = ld_frag(&Ab[(qr*16 + (lane&15))*72 + 32 + (lane>>4)*8]);
            #pragma unroll
            for (int dc=0;dc<4;++dc)
                acc[qr][dc] = mfma16(af, vb1[dc], acc[qr][dc]);
        }
    }
    // ---- epilogue: gate <- V * gate * 2^-24 ----
    #pragma unroll
    for (int qr=0; qr<4; ++qr){
        #pragma unroll
        for (int dc=0; dc<4; ++dc){
            #pragma unroll
            for (int r=0; r<4; ++r){
                int i = i0 + qr*16 + (lane>>4)*4 + r;
                int d = dhalf*512 + ds*64 + dc*16 + (lane&15);
                size_t go = ((size_t)(batch*SEQ + i))*HID + d;
                float g = gate[go];
                gate[go] = acc[qr][dc][r] * g * 0x1p-24f;
            }
        }
    }
}

// ---------- K5: out = Vg @ Wo + bo ----------
__global__ __launch_bounds__(256) void wo_kernel(const float* __restrict__ vg,
                                                 const float* __restrict__ Wo,
                                                 const float* __restrict__ bo,
                                                 float* out){
    int wave = threadIdx.x>>6, lane = threadIdx.x&63;
    int row  = blockIdx.x*4 + wave;
    const float* vr = vg + (size_t)row*HID;
    float po[8] = {};
    #pragma unroll
    for (int c=0;c<4;++c){
        float4 v = *(const float4*)(vr + c*256 + lane*4);
        float vv[4] = {v.x, v.y, v.z, v.w};
        #pragma unroll
        for (int e=0;e<4;++e){
            int col = c*256 + lane*4 + e;
            float4 w0 = *(const float4*)(Wo + (size_t)col*8);
            float4 w1 = *(const float4*)(Wo + (size_t)col*8 + 4);
            po[0] += vv[e]*w0.x; po[1] += vv[e]*w0.y; po[2] += vv[e]*w0.z; po[3] += vv[e]*w0.w;
            po[4] += vv[e]*w1.x; po[5] += vv[e]*w1.y; po[6] += vv[e]*w1.z; po[7] += vv[e]*w1.w;
        }
    }
    #pragma unroll
    for (int m=1;m<64;m<<=1){
        #pragma unroll
        for (int o=0;o<8;++o) po[o] += __shfl_xor(po[o], m, 64);
    }
    if (lane == 0){
        #pragma unroll
        for (int o=0;o<8;++o) out[(size_t)row*8 + o] = po[o] + bo[o];
    }
}

// ---------- launch ----------
extern "C" void kernel_launch(void* const* d_in, const int* in_sizes, int n_in,
                              void* d_out, int out_size, void* d_ws, size_t ws_size,
                              hipStream_t stream){
    const float* x    = (const float*)d_in[0];
    const float* ln_g = (const float*)d_in[1];
    const float* ln_b = (const float*)d_in[2];
    const float* Wh   = (const float*)d_in[3];
    const float* bh   = (const float*)d_in[4];
    const float* Wqk  = (const float*)d_in[5];
    const float* bqk  = (const float*)d_in[6];
    const float* gamma= (const float*)d_in[7];
    const float* beta = (const float*)d_in[8];
    const float* Wo   = (const float*)d_in[9];
    const float* bo   = (const float*)d_in[10];
    float* out = (float*)d_out;

    char* w = (char*)d_ws;
    auto alloc = [&](size_t bytes)->char*{
        char* p = w; w += (bytes + 255) & ~(size_t)255; return p;
    };
    u16* nh    = (u16*)alloc((size_t)ROWS*DIM*2);
    u16* whth  = (u16*)alloc((size_t)HID2*DIM*2);
    u16* wqkth = (u16*)alloc((size_t)QKD*DIM*2);
    u16* wqktl = (u16*)alloc((size_t)QKD*DIM*2);
    u16* q_f   = (u16*)alloc((size_t)ROWS*QKD*2);      // bf16, fragment-major
    u16* k_f   = (u16*)alloc((size_t)ROWS*QKD*2);      // bf16, fragment-major
    u16* v_f   = (u16*)alloc((size_t)BATCH*HID*SEQ*2); // bf16, fragment-major
    float* gate= (float*)alloc((size_t)ROWS*HID*4);

    prep_split<<<(HID2*DIM + QKD*DIM)/256, 256, 0, stream>>>(Wh, Wqk, whth, wqkth, wqktl);
    ln_kernel<<<ROWS/4, 256, 0, stream>>>(x, ln_g, ln_b, nh);
    gemm_h<<<2048, 256, 0, stream>>>(nh, whth, bh, v_f, gate);
    gemm_qk<<<ROWS/64, 256, 0, stream>>>(nh, wqkth, wqktl, bqk, gamma, beta, q_f, k_f);
    attn<<<512, 512, 0, stream>>>(q_f, k_f, v_f, gate);
    wo_kernel<<<ROWS/4, 256, 0, stream>>>(gate, Wo, bo, out);
}

// Round 13
// 273.071 us; speedup vs baseline: 1.3602x; 1.2567x over previous
//
#include <hip/hip_runtime.h>
#include <stdint.h>

#define DIM   512
#define QKD   128
#define HID   1024
#define HID2  2048
#define OUTD  8
#define BATCH 4
#define SEQ   4096
#define ROWS  (BATCH*SEQ)   // 16384
#define LN_EPS 1e-5f

typedef unsigned short u16;
typedef unsigned int   u32;
typedef __bf16 bf16x8 __attribute__((ext_vector_type(8)));
typedef float  f32x4  __attribute__((ext_vector_type(4)));

// ---------- helpers ----------
__device__ inline u16 f2bf(float f){
    uint32_t u = __builtin_bit_cast(uint32_t, f);
    u += 0x7FFFu + ((u >> 16) & 1u);   // RNE
    return (u16)(u >> 16);
}
__device__ inline float bf2f(u16 h){
    uint32_t u = ((uint32_t)h) << 16;
    return __builtin_bit_cast(float, u);
}
__device__ inline void split_bf16(float x, u16 &hi, u16 &lo){
    hi = f2bf(x);
    float r = x - bf2f(hi);
    lo = f2bf(r);
}
__device__ inline bf16x8 ld_frag(const u16* p){
    uint4 r = *reinterpret_cast<const uint4*>(p);
    return __builtin_bit_cast(bf16x8, r);
}
__device__ inline f32x4 mfma16(bf16x8 a, bf16x8 b, f32x4 c){
    return __builtin_amdgcn_mfma_f32_16x16x32_bf16(a, b, c, 0, 0, 0);
}
__device__ inline float silu(float x){ return x / (1.f + expf(-x)); }
// async global->LDS: PER-LANE global src addr, wave-uniform LDS base (+lane*16B)
__device__ inline void gload_lds16(const u16* g, u16* l){
    __builtin_amdgcn_global_load_lds(
        (const __attribute__((address_space(1))) u32*)g,
        (__attribute__((address_space(3))) u32*)l, 16, 0, 0);
}

// ---------- P: quantize/transpose weights ----------
// Wh -> bf16 (transposed); Wqk -> split hi/lo (transposed);
// Wo -> bf16 B-frag-major WoT[32 chunks][512]: lane=(o&15)+16*(dl>>3), e=dl&7, o>=8 -> 0
__global__ void prep_split(const float* __restrict__ Wh, const float* __restrict__ Wqk,
                           const float* __restrict__ Wo,
                           u16* whth, u16* wqkth, u16* wqktl, u16* woT){
    int tid = blockIdx.x*256 + threadIdx.x;
    const int NWH = HID2*DIM;            // 1048576
    if (tid < NWH){
        int k = tid & (DIM-1);
        int n = tid >> 9;
        whth[tid] = f2bf(Wh[(size_t)k*HID2 + n]);
    } else if (tid < NWH + QKD*DIM){
        int t2 = tid - NWH;
        int k = t2 & (DIM-1);
        int n = t2 >> 9;
        float w = Wqk[(size_t)k*QKD + n];
        u16 h,l; split_bf16(w,h,l);
        wqkth[t2]=h; wqktl[t2]=l;
    } else {
        int t3 = tid - NWH - QKD*DIM;
        if (t3 < 32*512){
            int dt = t3 >> 9, l = (t3 >> 3) & 63, e = t3 & 7;
            int o  = l & 15, dl = ((l >> 4) << 3) + e;
            woT[t3] = (o < OUTD) ? f2bf(Wo[(size_t)(dt*32 + dl)*OUTD + o]) : (u16)0;
        }
    }
}

// ---------- K1: layernorm -> bf16 ----------
__global__ __launch_bounds__(256) void ln_kernel(const float* __restrict__ x,
                                                 const float* __restrict__ g,
                                                 const float* __restrict__ b,
                                                 u16* nh){
    int wave = threadIdx.x >> 6, lane = threadIdx.x & 63;
    int row  = blockIdx.x*4 + wave;
    const float* xr = x + (size_t)row*DIM;
    float4 v0 = *(const float4*)(xr + lane*8);
    float4 v1 = *(const float4*)(xr + lane*8 + 4);
    float xs[8] = {v0.x,v0.y,v0.z,v0.w,v1.x,v1.y,v1.z,v1.w};
    float s = 0.f, q = 0.f;
    #pragma unroll
    for (int i=0;i<8;++i){ s += xs[i]; q += xs[i]*xs[i]; }
    #pragma unroll
    for (int m=1;m<64;m<<=1){ s += __shfl_xor(s,m,64); q += __shfl_xor(q,m,64); }
    float mean = s * (1.f/DIM);
    float var  = q * (1.f/DIM) - mean*mean;
    float rstd = rsqrtf(var + LN_EPS);
    float4 g0 = *(const float4*)(g + lane*8);
    float4 g1 = *(const float4*)(g + lane*8 + 4);
    float4 b0 = *(const float4*)(b + lane*8);
    float4 b1 = *(const float4*)(b + lane*8 + 4);
    float gs[8] = {g0.x,g0.y,g0.z,g0.w,g1.x,g1.y,g1.z,g1.w};
    float bs[8] = {b0.x,b0.y,b0.z,b0.w,b1.x,b1.y,b1.z,b1.w};
    u16 hh[8];
    #pragma unroll
    for (int i=0;i<8;++i){
        float nv = (xs[i]-mean)*rstd*gs[i] + bs[i];
        hh[i] = f2bf(nv);
    }
    size_t o = (size_t)row*DIM + lane*8;
    *(uint4*)(nh + o) = *(uint4*)hh;
}

// ---------- K2: hidden = silu(bf16(n) @ bf16(Wh) + bh) -> v_f (LDS-transposed) + gate ----------
__global__ __launch_bounds__(256,2) void gemm_h(
        const u16* __restrict__ nh,
        const u16* __restrict__ bth,
        const float* __restrict__ bh,
        u16* v_f, float* gate){
    __shared__ __align__(16) u16 SH2[16384];   // SA dbuf 2x4096 | SB dbuf 2x4096; VP overlay 16384
    u16* SA = SH2;          // [2][4096]
    u16* SB = SH2 + 8192;   // [2][4096]
    const int bid = blockIdx.x;
    const int xcd = bid & 7, bx = bid >> 3;
    const int nb = xcd*2 + (bx >> 7);    // 0..15
    const int mb = bx & 127;             // 0..127
    const int n0 = nb*128, m0 = mb*128;
    const int w = threadIdx.x >> 6, lane = threadIdx.x & 63;
    const int wr = w >> 1, wc = w & 1;

    auto stage = [&](int ks, int p){
        #pragma unroll
        for (int c=0;c<2;++c){
            int row = w*32 + c*16 + (lane>>2);       // 0..127
            const u16* gA = nh  + (size_t)(m0+row)*DIM + ks*32 + (lane&3)*8;
            const u16* gB = bth + (size_t)(n0+row)*DIM + ks*32 + (lane&3)*8;
            int off = w*1024 + c*512;
            gload_lds16(gA, &SA[p*4096 + off]);
            gload_lds16(gB, &SB[p*4096 + off]);
        }
    };

    stage(0, 0);
    __syncthreads();

    f32x4 acc[4][4] = {};
    for (int ks=0; ks<16; ++ks){
        const int p = ks & 1;
        if (ks < 15) stage(ks+1, p^1);
        bf16x8 Ah[4];
        #pragma unroll
        for (int rf=0;rf<4;++rf)
            Ah[rf] = ld_frag(&SA[p*4096 + (wr*64 + rf*16 + (lane&15))*32 + (lane>>4)*8]);
        #pragma unroll
        for (int cf=0;cf<4;++cf){
            bf16x8 Bh = ld_frag(&SB[p*4096 + (wc*64 + cf*16 + (lane&15))*32 + (lane>>4)*8]);
            #pragma unroll
            for (int rf=0;rf<4;++rf)
                acc[rf][cf] = mfma16(Ah[rf], Bh, acc[rf][cf]);
        }
        __syncthreads();
    }
    if (nb < 8){
        // v-path: build frag-major tile in LDS (32 frags x 512 u16 = 32 KB overlay),
        // then fully-coalesced 16B stores (8 x uint4 per thread = 64 u16).
        u16* VP = SH2;
        #pragma unroll
        for (int rf=0;rf<4;++rf){
            #pragma unroll
            for (int cf=0;cf<4;++cf){
                #pragma unroll
                for (int r=0;r<4;++r){
                    int row_rel = wr*64 + rf*16 + (lane>>4)*4 + r;
                    int col_rel = wc*64 + cf*16 + (lane&15);
                    float s = silu(acc[rf][cf][r] + bh[n0 + col_rel]);
                    int f = ((row_rel>>5)<<3) | (col_rel>>4);
                    VP[f*512 + ((col_rel&15) + (((row_rel>>3)&3)<<4))*8 + (row_rel&7)] = f2bf(s);
                }
            }
        }
        __syncthreads();
        int fi = threadIdx.x >> 3, pt = threadIdx.x & 7;
        int b  = m0 >> 12, itb = (m0 & 4095) >> 5;
        size_t gbase = (((size_t)b*128 + itb + (fi>>3))*64 + (n0>>4) + (fi&7))*512;
        #pragma unroll
        for (int c2=0;c2<8;++c2)
            *(uint4*)(v_f + gbase + pt*64 + c2*8) = *(uint4*)&VP[fi*512 + pt*64 + c2*8];
    } else {
        #pragma unroll
        for (int rf=0;rf<4;++rf){
            #pragma unroll
            for (int cf=0;cf<4;++cf){
                #pragma unroll
                for (int r=0;r<4;++r){
                    int row = m0 + wr*64 + rf*16 + (lane>>4)*4 + r;
                    int col = n0 + wc*64 + cf*16 + (lane&15);
                    float s = silu(acc[rf][cf][r] + bh[col]);
                    gate[(size_t)row*HID + (col - HID)] = s;
                }
            }
        }
    }
}

// ---------- K3: Z = silu(bf16(n) @ (Wqk_hi+Wqk_lo) + bqk); q,k bf16 frag-major ----------
__global__ __launch_bounds__(256,2) void gemm_qk(
        const u16* __restrict__ nh,
        const u16* __restrict__ bth, const u16* __restrict__ btl,
        const float* __restrict__ bqk, const float* __restrict__ gamma,
        const float* __restrict__ beta,
        u16* q_f, u16* k_f){
    __shared__ __align__(16) u16 At[64][40];
    __shared__ __align__(16) u16 Bt[2][128][40];
    int m0 = blockIdx.x * 64;
    int wave = threadIdx.x>>6, lane = threadIdx.x&63;
    int wr = wave>>1, wc = wave&1;   // wave: 32q x 64n
    f32x4 acc[2][4] = {};
    for (int ks=0; ks<16; ++ks){
        {
            int row = threadIdx.x>>2, ch = threadIdx.x&3;
            *(uint4*)&At[row][ch*8] = *(const uint4*)(nh + (size_t)(m0+row)*DIM + ks*32 + ch*8);
        }
        #pragma unroll
        for (int r=0;r<2;++r){
            int idx = r*256 + threadIdx.x;
            int row = idx>>2, ch = idx&3;
            size_t gb = (size_t)row*DIM + ks*32 + ch*8;
            *(uint4*)&Bt[0][row][ch*8] = *(const uint4*)(bth + gb);
            *(uint4*)&Bt[1][row][ch*8] = *(const uint4*)(btl + gb);
        }
        __syncthreads();
        bf16x8 Ah[2];
        #pragma unroll
        for (int rf=0;rf<2;++rf)
            Ah[rf] = ld_frag(&At[wr*32 + rf*16 + (lane&15)][(lane>>4)*8]);
        #pragma unroll
        for (int cf=0;cf<4;++cf){
            bf16x8 Bh = ld_frag(&Bt[0][wc*64 + cf*16 + (lane&15)][(lane>>4)*8]);
            bf16x8 Bl = ld_frag(&Bt[1][wc*64 + cf*16 + (lane&15)][(lane>>4)*8]);
            #pragma unroll
            for (int rf=0;rf<2;++rf){
                acc[rf][cf] = mfma16(Ah[rf], Bh, acc[rf][cf]);
                acc[rf][cf] = mfma16(Ah[rf], Bl, acc[rf][cf]);
            }
        }
        __syncthreads();
    }
    #pragma unroll
    for (int rf=0;rf<2;++rf){
        #pragma unroll
        for (int cf=0;cf<4;++cf){
            #pragma unroll
            for (int r=0;r<4;++r){
                int row = m0 + wr*32 + rf*16 + (lane>>4)*4 + r;
                int col = wc*64 + cf*16 + (lane&15);
                float z = silu(acc[rf][cf][r] + bqk[col]);
                float qv = z*gamma[col]       + beta[col];
                float kv = z*gamma[QKD + col] + beta[QKD + col];
                size_t lane_e = (size_t)((row&15) + (((col>>3)&3)<<4))*8 + (col&7);
                size_t it4ks  = (size_t)(row>>4)*4 + (col>>5);
                q_f[it4ks*512 + lane_e] = f2bf(qv);
                k_f[it4ks*512 + lane_e] = f2bf(kv);
            }
        }
    }
}

// ---------- K4: fused squared-relu attention + Wo projection ----------
// Main loop IDENTICAL to round-9/11 (known-good 166us). Epilogue: Vg=acc*gate*2^-24
// -> bf16 frag-major in LDS (overlay) -> 16 MFMA vs WoT -> per-block out-partials.
__global__ __launch_bounds__(512,4) void attn(
        const u16* __restrict__ q_f, const u16* __restrict__ k_f,
        const u16* __restrict__ v_f, const float* __restrict__ gate,
        const u16* __restrict__ woT, float* part){
    __shared__ __align__(16) u16 SH[33792];   // QL 8192 | KT 2x8192 | AT 2x4608
    u16* QL = SH;
    u16* KT0 = SH + 8192;
    u16* AT0 = SH + 24576;
    const int bid = blockIdx.x, xcd = bid & 7;
    const int batch = xcd >> 1, dhalf = xcd & 1, qt = bid >> 3;
    const int i0 = qt * 64;
    const int w = threadIdx.x >> 6, lane = threadIdx.x & 63;
    const int fr = w >> 1, fc = w & 1;    // QK: 16q strip x 32j half
    const int ds = w;                     // PV: 64d slice

    // ---- stage Q once + K(0), async ----
    {
        size_t qbase = ((size_t)(batch*256 + qt*4))*2048;
        size_t kbase = ((size_t)(batch*256 + 0*4))*2048;
        #pragma unroll
        for (int c=0;c<2;++c){
            int off = w*1024 + c*512;
            gload_lds16(q_f + qbase + off + lane*8, &QL[off]);
            gload_lds16(k_f + kbase + off + lane*8, &KT0[off]);
        }
    }
    __syncthreads();

    f32x4 acc[4][4] = {};   // 64q x 64d per wave
    for (int kt=0; kt<64; ++kt){
        const int p = kt & 1;
        {
            size_t kbase = ((size_t)(batch*256 + (((kt+1)&63))*4))*2048;
            #pragma unroll
            for (int c=0;c<2;++c){
                int off = w*1024 + c*512;
                gload_lds16(k_f + kbase + off + lane*8, &KT0[(p^1)*8192 + off]);
            }
        }
        bf16x8 vb0[4];
        #pragma unroll
        for (int dc=0;dc<4;++dc)
            vb0[dc] = ld_frag(v_f + (((size_t)(batch*128 + kt*2))*64
                              + dhalf*32 + ds*4 + dc)*512 + lane*8);
        f32x4 sacc[2] = {};
        #pragma unroll
        for (int ks=0;ks<4;++ks){
            bf16x8 qa = ld_frag(&QL[fr*2048 + ks*512 + lane*8]);
            #pragma unroll
            for (int t=0;t<2;++t){
                bf16x8 kb = ld_frag(&KT0[p*8192 + (fc*2 + t)*2048 + ks*512 + lane*8]);
                sacc[t] = mfma16(qa, kb, sacc[t]);
            }
        }
        u16* Ab = AT0 + p*4608;
        #pragma unroll
        for (int t=0;t<2;++t){
            #pragma unroll
            for (int r=0;r<4;++r){
                float s = sacc[t][r];
                s = s > 0.f ? s*s : 0.f;
                int q = fr*16 + (lane>>4)*4 + r;
                int j = fc*32 + t*16 + (lane&15);
                Ab[q*72 + j] = f2bf(s);
            }
        }
        __syncthreads();
        #pragma unroll
        for (int qr=0;qr<4;++qr){
            bf16x8 af = ld_frag(&Ab[(qr*16 + (lane&15))*72 + (lane>>4)*8]);
            #pragma unroll
            for (int dc=0;dc<4;++dc)
                acc[qr][dc] = mfma16(af, vb0[dc], acc[qr][dc]);
        }
        bf16x8 vb1[4];
        #pragma unroll
        for (int dc=0;dc<4;++dc)
            vb1[dc] = ld_frag(v_f + (((size_t)(batch*128 + kt*2 + 1))*64
                              + dhalf*32 + ds*4 + dc)*512 + lane*8);
        #pragma unroll
        for (int qr=0;qr<4;++qr){
            bf16x8 af = ld_frag(&Ab[(qr*16 + (lane&15))*72 + 32 + (lane>>4)*8]);
            #pragma unroll
            for (int dc=0;dc<4;++dc)
                acc[qr][dc] = mfma16(af, vb1[dc], acc[qr][dc]);
        }
    }
    // ---- epilogue: Vg = acc*gate*2^-24 -> LDS (A-frag layout) -> @ WoT -> part ----
    __syncthreads();   // done with QL/KT/AT reads; overlay VgL
    u16* VgL = SH;     // 16 dchunks x 4 qtiles x 512 u16 = 32768 u16 = 64 KB
    #pragma unroll
    for (int qr=0; qr<4; ++qr){
        #pragma unroll
        for (int dc=0; dc<4; ++dc){
            #pragma unroll
            for (int r=0; r<4; ++r){
                int i_local = qr*16 + (lane>>4)*4 + r;
                int d_local = ds*64 + dc*16 + (lane&15);
                float g = gate[((size_t)(batch*SEQ + i0 + i_local))*HID + dhalf*512 + d_local];
                float vg = acc[qr][dc][r] * g * 0x1p-24f;
                int dchunk = (d_local >> 5);
                int dl = d_local & 31;
                int q16 = (lane>>4)*4 + r;
                VgL[(dchunk*4 + qr)*512 + (q16 + ((dl>>3)<<4))*8 + (dl&7)] = f2bf(vg);
            }
        }
    }
    __syncthreads();
    if (w < 4){
        f32x4 oc = {};
        #pragma unroll
        for (int ch=0; ch<16; ++ch){
            bf16x8 a = ld_frag(&VgL[(ch*4 + w)*512 + lane*8]);
            bf16x8 b = ld_frag(woT + ((size_t)(dhalf*16 + ch))*512 + lane*8);
            oc = mfma16(a, b, oc);
        }
        if ((lane & 15) < OUTD){
            size_t base = ((size_t)dhalf*ROWS + batch*SEQ + i0 + w*16)*OUTD;
            #pragma unroll
            for (int r=0;r<4;++r)
                part[base + (size_t)((lane>>4)*4 + r)*OUTD + (lane&15)] = oc[r];
        }
    }
}

// ---------- K5: out = part0 + part1 + bo ----------
__global__ __launch_bounds__(256) void reduce_out(const float* __restrict__ part,
                                                  const float* __restrict__ bo,
                                                  float* __restrict__ out){
    int idx = (blockIdx.x*256 + threadIdx.x)*4;   // ROWS*8 = 131072 floats
    float4 a = *(const float4*)(part + idx);
    float4 b = *(const float4*)(part + (size_t)ROWS*OUTD + idx);
    float4 c = *(const float4*)(bo + (idx & 7));
    float4 o = {a.x+b.x+c.x, a.y+b.y+c.y, a.z+b.z+c.z, a.w+b.w+c.w};
    *(float4*)(out + idx) = o;
}

// ---------- launch ----------
extern "C" void kernel_launch(void* const* d_in, const int* in_sizes, int n_in,
                              void* d_out, int out_size, void* d_ws, size_t ws_size,
                              hipStream_t stream){
    const float* x    = (const float*)d_in[0];
    const float* ln_g = (const float*)d_in[1];
    const float* ln_b = (const float*)d_in[2];
    const float* Wh   = (const float*)d_in[3];
    const float* bh   = (const float*)d_in[4];
    const float* Wqk  = (const float*)d_in[5];
    const float* bqk  = (const float*)d_in[6];
    const float* gamma= (const float*)d_in[7];
    const float* beta = (const float*)d_in[8];
    const float* Wo   = (const float*)d_in[9];
    const float* bo   = (const float*)d_in[10];
    float* out = (float*)d_out;

    char* w = (char*)d_ws;
    auto alloc = [&](size_t bytes)->char*{
        char* p = w; w += (bytes + 255) & ~(size_t)255; return p;
    };
    u16* nh    = (u16*)alloc((size_t)ROWS*DIM*2);
    u16* whth  = (u16*)alloc((size_t)HID2*DIM*2);
    u16* wqkth = (u16*)alloc((size_t)QKD*DIM*2);
    u16* wqktl = (u16*)alloc((size_t)QKD*DIM*2);
    u16* woT   = (u16*)alloc((size_t)32*512*2);
    u16* q_f   = (u16*)alloc((size_t)ROWS*QKD*2);
    u16* k_f   = (u16*)alloc((size_t)ROWS*QKD*2);
    u16* v_f   = (u16*)alloc((size_t)BATCH*HID*SEQ*2);
    float* gate= (float*)alloc((size_t)ROWS*HID*4);
    float* part= (float*)alloc((size_t)2*ROWS*OUTD*4);

    prep_split<<<(HID2*DIM + QKD*DIM + 32*512)/256, 256, 0, stream>>>(Wh, Wqk, Wo, whth, wqkth, wqktl, woT);
    ln_kernel<<<ROWS/4, 256, 0, stream>>>(x, ln_g, ln_b, nh);
    gemm_h<<<2048, 256, 0, stream>>>(nh, whth, bh, v_f, gate);
    gemm_qk<<<ROWS/64, 256, 0, stream>>>(nh, wqkth, wqktl, bqk, gamma, beta, q_f, k_f);
    attn<<<512, 512, 0, stream>>>(q_f, k_f, v_f, gate, woT, part);
    reduce_out<<<ROWS*OUTD/1024, 256, 0, stream>>>(part, bo, out);
}

// Round 14
// 266.653 us; speedup vs baseline: 1.3929x; 1.0241x over previous
//
#include <hip/hip_runtime.h>
#include <stdint.h>

#define DIM   512
#define QKD   128
#define HID   1024
#define HID2  2048
#define OUTD  8
#define BATCH 4
#define SEQ   4096
#define ROWS  (BATCH*SEQ)   // 16384
#define LN_EPS 1e-5f

typedef unsigned short u16;
typedef unsigned int   u32;
typedef __bf16 bf16x8 __attribute__((ext_vector_type(8)));
typedef float  f32x4  __attribute__((ext_vector_type(4)));

// ---------- helpers ----------
__device__ inline u16 f2bf(float f){
    uint32_t u = __builtin_bit_cast(uint32_t, f);
    u += 0x7FFFu + ((u >> 16) & 1u);   // RNE
    return (u16)(u >> 16);
}
__device__ inline float bf2f(u16 h){
    uint32_t u = ((uint32_t)h) << 16;
    return __builtin_bit_cast(float, u);
}
__device__ inline void split_bf16(float x, u16 &hi, u16 &lo){
    hi = f2bf(x);
    float r = x - bf2f(hi);
    lo = f2bf(r);
}
__device__ inline bf16x8 ld_frag(const u16* p){
    uint4 r = *reinterpret_cast<const uint4*>(p);
    return __builtin_bit_cast(bf16x8, r);
}
__device__ inline f32x4 mfma16(bf16x8 a, bf16x8 b, f32x4 c){
    return __builtin_amdgcn_mfma_f32_16x16x32_bf16(a, b, c, 0, 0, 0);
}
__device__ inline float silu(float x){ return x / (1.f + expf(-x)); }
// async global->LDS: PER-LANE global src addr, wave-uniform LDS base (+lane*16B)
__device__ inline void gload_lds16(const u16* g, u16* l){
    __builtin_amdgcn_global_load_lds(
        (const __attribute__((address_space(1))) u32*)g,
        (__attribute__((address_space(3))) u32*)l, 16, 0, 0);
}

// ---------- P: quantize/transpose weights ----------
// Wh -> bf16 (transposed); Wqk -> split hi/lo (transposed);
// Wo -> bf16 B-frag-major WoT[32 chunks][512]: lane=(o&15)+16*(dl>>3), e=dl&7, o>=8 -> 0
__global__ void prep_split(const float* __restrict__ Wh, const float* __restrict__ Wqk,
                           const float* __restrict__ Wo,
                           u16* whth, u16* wqkth, u16* wqktl, u16* woT){
    int tid = blockIdx.x*256 + threadIdx.x;
    const int NWH = HID2*DIM;            // 1048576
    if (tid < NWH){
        int k = tid & (DIM-1);
        int n = tid >> 9;
        whth[tid] = f2bf(Wh[(size_t)k*HID2 + n]);
    } else if (tid < NWH + QKD*DIM){
        int t2 = tid - NWH;
        int k = t2 & (DIM-1);
        int n = t2 >> 9;
        float w = Wqk[(size_t)k*QKD + n];
        u16 h,l; split_bf16(w,h,l);
        wqkth[t2]=h; wqktl[t2]=l;
    } else {
        int t3 = tid - NWH - QKD*DIM;
        if (t3 < 32*512){
            int dt = t3 >> 9, l = (t3 >> 3) & 63, e = t3 & 7;
            int o  = l & 15, dl = ((l >> 4) << 3) + e;
            woT[t3] = (o < OUTD) ? f2bf(Wo[(size_t)(dt*32 + dl)*OUTD + o]) : (u16)0;
        }
    }
}

// ---------- K1: layernorm -> bf16 ----------
__global__ __launch_bounds__(256) void ln_kernel(const float* __restrict__ x,
                                                 const float* __restrict__ g,
                                                 const float* __restrict__ b,
                                                 u16* nh){
    int wave = threadIdx.x >> 6, lane = threadIdx.x & 63;
    int row  = blockIdx.x*4 + wave;
    const float* xr = x + (size_t)row*DIM;
    float4 v0 = *(const float4*)(xr + lane*8);
    float4 v1 = *(const float4*)(xr + lane*8 + 4);
    float xs[8] = {v0.x,v0.y,v0.z,v0.w,v1.x,v1.y,v1.z,v1.w};
    float s = 0.f, q = 0.f;
    #pragma unroll
    for (int i=0;i<8;++i){ s += xs[i]; q += xs[i]*xs[i]; }
    #pragma unroll
    for (int m=1;m<64;m<<=1){ s += __shfl_xor(s,m,64); q += __shfl_xor(q,m,64); }
    float mean = s * (1.f/DIM);
    float var  = q * (1.f/DIM) - mean*mean;
    float rstd = rsqrtf(var + LN_EPS);
    float4 g0 = *(const float4*)(g + lane*8);
    float4 g1 = *(const float4*)(g + lane*8 + 4);
    float4 b0 = *(const float4*)(b + lane*8);
    float4 b1 = *(const float4*)(b + lane*8 + 4);
    float gs[8] = {g0.x,g0.y,g0.z,g0.w,g1.x,g1.y,g1.z,g1.w};
    float bs[8] = {b0.x,b0.y,b0.z,b0.w,b1.x,b1.y,b1.z,b1.w};
    u16 hh[8];
    #pragma unroll
    for (int i=0;i<8;++i){
        float nv = (xs[i]-mean)*rstd*gs[i] + bs[i];
        hh[i] = f2bf(nv);
    }
    size_t o = (size_t)row*DIM + lane*8;
    *(uint4*)(nh + o) = *(uint4*)hh;
}

// ---------- K2: hidden = silu(bf16(n) @ bf16(Wh) + bh) -> v_f + gate_f (bf16 C-frags) ----------
__global__ __launch_bounds__(256,2) void gemm_h(
        const u16* __restrict__ nh,
        const u16* __restrict__ bth,
        const float* __restrict__ bh,
        u16* v_f, u16* gate_f){
    __shared__ __align__(16) u16 SH2[16384];   // SA dbuf 2x4096 | SB dbuf 2x4096; VP overlay
    u16* SA = SH2;          // [2][4096]
    u16* SB = SH2 + 8192;   // [2][4096]
    const int bid = blockIdx.x;
    const int xcd = bid & 7, bx = bid >> 3;
    const int nb = xcd*2 + (bx >> 7);    // 0..15
    const int mb = bx & 127;             // 0..127
    const int n0 = nb*128, m0 = mb*128;
    const int w = threadIdx.x >> 6, lane = threadIdx.x & 63;
    const int wr = w >> 1, wc = w & 1;

    auto stage = [&](int ks, int p){
        #pragma unroll
        for (int c=0;c<2;++c){
            int row = w*32 + c*16 + (lane>>2);       // 0..127
            const u16* gA = nh  + (size_t)(m0+row)*DIM + ks*32 + (lane&3)*8;
            const u16* gB = bth + (size_t)(n0+row)*DIM + ks*32 + (lane&3)*8;
            int off = w*1024 + c*512;
            gload_lds16(gA, &SA[p*4096 + off]);
            gload_lds16(gB, &SB[p*4096 + off]);
        }
    };

    stage(0, 0);
    __syncthreads();

    f32x4 acc[4][4] = {};
    for (int ks=0; ks<16; ++ks){
        const int p = ks & 1;
        if (ks < 15) stage(ks+1, p^1);
        bf16x8 Ah[4];
        #pragma unroll
        for (int rf=0;rf<4;++rf)
            Ah[rf] = ld_frag(&SA[p*4096 + (wr*64 + rf*16 + (lane&15))*32 + (lane>>4)*8]);
        #pragma unroll
        for (int cf=0;cf<4;++cf){
            bf16x8 Bh = ld_frag(&SB[p*4096 + (wc*64 + cf*16 + (lane&15))*32 + (lane>>4)*8]);
            #pragma unroll
            for (int rf=0;rf<4;++rf)
                acc[rf][cf] = mfma16(Ah[rf], Bh, acc[rf][cf]);
        }
        __syncthreads();
    }
    if (nb < 8){
        // v-path: build frag-major tile in LDS (32 frags x 512 u16 = 32 KB overlay),
        // then fully-coalesced 16B stores (8 x uint4 per thread).
        u16* VP = SH2;
        #pragma unroll
        for (int rf=0;rf<4;++rf){
            #pragma unroll
            for (int cf=0;cf<4;++cf){
                #pragma unroll
                for (int r=0;r<4;++r){
                    int row_rel = wr*64 + rf*16 + (lane>>4)*4 + r;
                    int col_rel = wc*64 + cf*16 + (lane&15);
                    float s = silu(acc[rf][cf][r] + bh[n0 + col_rel]);
                    int f = ((row_rel>>5)<<3) | (col_rel>>4);
                    VP[f*512 + ((col_rel&15) + (((row_rel>>3)&3)<<4))*8 + (row_rel&7)] = f2bf(s);
                }
            }
        }
        __syncthreads();
        int fi = threadIdx.x >> 3, pt = threadIdx.x & 7;
        int b  = m0 >> 12, itb = (m0 & 4095) >> 5;
        size_t gbase = (((size_t)b*128 + itb + (fi>>3))*64 + (n0>>4) + (fi&7))*512;
        #pragma unroll
        for (int c2=0;c2<8;++c2)
            *(uint4*)(v_f + gbase + pt*64 + c2*8) = *(uint4*)&VP[fi*512 + pt*64 + c2*8];
    } else {
        // gate-path: store bf16 in MFMA C-fragment layout (coalesced uint2/lane/frag).
        // gate_f[(b*256 + it)*64 + dt][lane*4 + r], it = i>>4, dt = d>>4
        const int b  = m0 >> 12;
        const int i_rel = m0 & 4095;
        #pragma unroll
        for (int rf=0;rf<4;++rf){
            const int it = (i_rel + wr*64 + rf*16) >> 4;
            #pragma unroll
            for (int cf=0;cf<4;++cf){
                const int dt = ((nb-8)*128 + wc*64 + cf*16) >> 4;
                u16 gv[4];
                #pragma unroll
                for (int r=0;r<4;++r){
                    int col = n0 + wc*64 + cf*16 + (lane&15);
                    gv[r] = f2bf(silu(acc[rf][cf][r] + bh[col]));
                }
                size_t fo = (((size_t)b*256 + it)*64 + dt)*256 + lane*4;
                *(uint2*)(gate_f + fo) = *(uint2*)gv;
            }
        }
    }
}

// ---------- K3: Z = silu(bf16(n) @ (Wqk_hi+Wqk_lo) + bqk); q,k bf16 frag-major ----------
// m97 structure: gload_lds staging (A + B hi/lo), dbuf, 1 barrier/ks. M=64, grid 256.
__global__ __launch_bounds__(256,2) void gemm_qk(
        const u16* __restrict__ nh,
        const u16* __restrict__ bth, const u16* __restrict__ btl,
        const float* __restrict__ bqk, const float* __restrict__ gamma,
        const float* __restrict__ beta,
        u16* q_f, u16* k_f){
    __shared__ __align__(16) u16 SA [2][2048];   // 64 x 32
    __shared__ __align__(16) u16 SB0[2][4096];   // 128 x 32
    __shared__ __align__(16) u16 SB1[2][4096];
    int m0 = blockIdx.x * 64;
    int w = threadIdx.x >> 6, lane = threadIdx.x & 63;
    int wr = w >> 1, wc = w & 1;   // wave: 32q x 64n

    auto stage = [&](int ks, int p){
        {   // A: 64 rows, 1 chunk per wave
            int row = w*16 + (lane>>2);
            gload_lds16(nh + (size_t)(m0+row)*DIM + ks*32 + (lane&3)*8, &SA[p][w*512]);
        }
        #pragma unroll
        for (int c=0;c<2;++c){
            int row = w*32 + c*16 + (lane>>2);   // 0..127
            int off = w*1024 + c*512;
            gload_lds16(bth + (size_t)row*DIM + ks*32 + (lane&3)*8, &SB0[p][off]);
            gload_lds16(btl + (size_t)row*DIM + ks*32 + (lane&3)*8, &SB1[p][off]);
        }
    };

    stage(0, 0);
    __syncthreads();

    f32x4 acc[2][4] = {};
    for (int ks=0; ks<16; ++ks){
        const int p = ks & 1;
        if (ks < 15) stage(ks+1, p^1);
        bf16x8 Ah[2];
        #pragma unroll
        for (int rf=0;rf<2;++rf)
            Ah[rf] = ld_frag(&SA[p][(wr*32 + rf*16 + (lane&15))*32 + (lane>>4)*8]);
        #pragma unroll
        for (int cf=0;cf<4;++cf){
            bf16x8 Bh = ld_frag(&SB0[p][(wc*64 + cf*16 + (lane&15))*32 + (lane>>4)*8]);
            bf16x8 Bl = ld_frag(&SB1[p][(wc*64 + cf*16 + (lane&15))*32 + (lane>>4)*8]);
            #pragma unroll
            for (int rf=0;rf<2;++rf){
                acc[rf][cf] = mfma16(Ah[rf], Bh, acc[rf][cf]);
                acc[rf][cf] = mfma16(Ah[rf], Bl, acc[rf][cf]);
            }
        }
        __syncthreads();
    }
    #pragma unroll
    for (int rf=0;rf<2;++rf){
        #pragma unroll
        for (int cf=0;cf<4;++cf){
            #pragma unroll
            for (int r=0;r<4;++r){
                int row = m0 + wr*32 + rf*16 + (lane>>4)*4 + r;
                int col = wc*64 + cf*16 + (lane&15);
                float z = silu(acc[rf][cf][r] + bqk[col]);
                float qv = z*gamma[col]       + beta[col];
                float kv = z*gamma[QKD + col] + beta[QKD + col];
                size_t lane_e = (size_t)((row&15) + (((col>>3)&3)<<4))*8 + (col&7);
                size_t it4ks  = (size_t)(row>>4)*4 + (col>>5);
                q_f[it4ks*512 + lane_e] = f2bf(qv);
                k_f[it4ks*512 + lane_e] = f2bf(kv);
            }
        }
    }
}

// ---------- K4: fused squared-relu attention + Wo projection ----------
// Main loop IDENTICAL to round-9/11/13 (known-good). Epilogue: Vg=acc*gate*2^-24
// (gate read as bf16 C-frags, coalesced) -> bf16 frag-major LDS -> 16 MFMA vs WoT
// -> per-block out-partials.
__global__ __launch_bounds__(512,4) void attn(
        const u16* __restrict__ q_f, const u16* __restrict__ k_f,
        const u16* __restrict__ v_f, const u16* __restrict__ gate_f,
        const u16* __restrict__ woT, float* part){
    __shared__ __align__(16) u16 SH[33792];   // QL 8192 | KT 2x8192 | AT 2x4608
    u16* QL = SH;
    u16* KT0 = SH + 8192;
    u16* AT0 = SH + 24576;
    const int bid = blockIdx.x, xcd = bid & 7;
    const int batch = xcd >> 1, dhalf = xcd & 1, qt = bid >> 3;
    const int i0 = qt * 64;
    const int w = threadIdx.x >> 6, lane = threadIdx.x & 63;
    const int fr = w >> 1, fc = w & 1;    // QK: 16q strip x 32j half
    const int ds = w;                     // PV: 64d slice

    // ---- stage Q once + K(0), async ----
    {
        size_t qbase = ((size_t)(batch*256 + qt*4))*2048;
        size_t kbase = ((size_t)(batch*256 + 0*4))*2048;
        #pragma unroll
        for (int c=0;c<2;++c){
            int off = w*1024 + c*512;
            gload_lds16(q_f + qbase + off + lane*8, &QL[off]);
            gload_lds16(k_f + kbase + off + lane*8, &KT0[off]);
        }
    }
    __syncthreads();

    f32x4 acc[4][4] = {};   // 64q x 64d per wave
    for (int kt=0; kt<64; ++kt){
        const int p = kt & 1;
        {
            size_t kbase = ((size_t)(batch*256 + (((kt+1)&63))*4))*2048;
            #pragma unroll
            for (int c=0;c<2;++c){
                int off = w*1024 + c*512;
                gload_lds16(k_f + kbase + off + lane*8, &KT0[(p^1)*8192 + off]);
            }
        }
        bf16x8 vb0[4];
        #pragma unroll
        for (int dc=0;dc<4;++dc)
            vb0[dc] = ld_frag(v_f + (((size_t)(batch*128 + kt*2))*64
                              + dhalf*32 + ds*4 + dc)*512 + lane*8);
        f32x4 sacc[2] = {};
        #pragma unroll
        for (int ks=0;ks<4;++ks){
            bf16x8 qa = ld_frag(&QL[fr*2048 + ks*512 + lane*8]);
            #pragma unroll
            for (int t=0;t<2;++t){
                bf16x8 kb = ld_frag(&KT0[p*8192 + (fc*2 + t)*2048 + ks*512 + lane*8]);
                sacc[t] = mfma16(qa, kb, sacc[t]);
            }
        }
        u16* Ab = AT0 + p*4608;
        #pragma unroll
        for (int t=0;t<2;++t){
            #pragma unroll
            for (int r=0;r<4;++r){
                float s = sacc[t][r];
                s = s > 0.f ? s*s : 0.f;
                int q = fr*16 + (lane>>4)*4 + r;
                int j = fc*32 + t*16 + (lane&15);
                Ab[q*72 + j] = f2bf(s);
            }
        }
        __syncthreads();
        #pragma unroll
        for (int qr=0;qr<4;++qr){
            bf16x8 af = ld_frag(&Ab[(qr*16 + (lane&15))*72 + (lane>>4)*8]);
            #pragma unroll
            for (int dc=0;dc<4;++dc)
                acc[qr][dc] = mfma16(af, vb0[dc], acc[qr][dc]);
        }
        bf16x8 vb1[4];
        #pragma unroll
        for (int dc=0;dc<4;++dc)
            vb1[dc] = ld_frag(v_f + (((size_t)(batch*128 + kt*2 + 1))*64
                              + dhalf*32 + ds*4 + dc)*512 + lane*8);
        #pragma unroll
        for (int qr=0;qr<4;++qr){
            bf16x8 af = ld_frag(&Ab[(qr*16 + (lane&15))*72 + 32 + (lane>>4)*8]);
            #pragma unroll
            for (int dc=0;dc<4;++dc)
                acc[qr][dc] = mfma16(af, vb1[dc], acc[qr][dc]);
        }
    }
    // ---- epilogue: Vg = acc*gate*2^-24 -> LDS (A-frag layout) -> @ WoT -> part ----
    __syncthreads();   // done with QL/KT/AT reads; overlay VgL
    u16* VgL = SH;     // 16 dchunks x 4 qtiles x 512 u16 = 64 KB
    #pragma unroll
    for (int qr=0; qr<4; ++qr){
        #pragma unroll
        for (int dc=0; dc<4; ++dc){
            // gate C-frag: it = qt*4+qr, dt = dhalf*32 + ds*4 + dc
            size_t fo = (((size_t)batch*256 + qt*4 + qr)*64 + dhalf*32 + ds*4 + dc)*256 + lane*4;
            uint2 gvp = *(const uint2*)(gate_f + fo);
            u16* gv = (u16*)&gvp;
            #pragma unroll
            for (int r=0; r<4; ++r){
                int d_local = ds*64 + dc*16 + (lane&15);
                float vg = acc[qr][dc][r] * bf2f(gv[r]) * 0x1p-24f;
                int dchunk = (d_local >> 5);
                int dl = d_local & 31;
                int q16 = (lane>>4)*4 + r;
                VgL[(dchunk*4 + qr)*512 + (q16 + ((dl>>3)<<4))*8 + (dl&7)] = f2bf(vg);
            }
        }
    }
    __syncthreads();
    if (w < 4){
        f32x4 oc = {};
        #pragma unroll
        for (int ch=0; ch<16; ++ch){
            bf16x8 a = ld_frag(&VgL[(ch*4 + w)*512 + lane*8]);
            bf16x8 b = ld_frag(woT + ((size_t)(dhalf*16 + ch))*512 + lane*8);
            oc = mfma16(a, b, oc);
        }
        if ((lane & 15) < OUTD){
            size_t base = ((size_t)dhalf*ROWS + batch*SEQ + i0 + w*16)*OUTD;
            #pragma unroll
            for (int r=0;r<4;++r)
                part[base + (size_t)((lane>>4)*4 + r)*OUTD + (lane&15)] = oc[r];
        }
    }
}

// ---------- K5: out = part0 + part1 + bo ----------
__global__ __launch_bounds__(256) void reduce_out(const float* __restrict__ part,
                                                  const float* __restrict__ bo,
                                                  float* __restrict__ out){
    int idx = (blockIdx.x*256 + threadIdx.x)*4;   // ROWS*8 = 131072 floats
    float4 a = *(const float4*)(part + idx);
    float4 b = *(const float4*)(part + (size_t)ROWS*OUTD + idx);
    float4 c = *(const float4*)(bo + (idx & 7));
    float4 o = {a.x+b.x+c.x, a.y+b.y+c.y, a.z+b.z+c.z, a.w+b.w+c.w};
    *(float4*)(out + idx) = o;
}

// ---------- launch ----------
extern "C" void kernel_launch(void* const* d_in, const int* in_sizes, int n_in,
                              void* d_out, int out_size, void* d_ws, size_t ws_size,
                              hipStream_t stream){
    const float* x    = (const float*)d_in[0];
    const float* ln_g = (const float*)d_in[1];
    const float* ln_b = (const float*)d_in[2];
    const float* Wh   = (const float*)d_in[3];
    const float* bh   = (const float*)d_in[4];
    const float* Wqk  = (const float*)d_in[5];
    const float* bqk  = (const float*)d_in[6];
    const float* gamma= (const float*)d_in[7];
    const float* beta = (const float*)d_in[8];
    const float* Wo   = (const float*)d_in[9];
    const float* bo   = (const float*)d_in[10];
    float* out = (float*)d_out;

    char* w = (char*)d_ws;
    auto alloc = [&](size_t bytes)->char*{
        char* p = w; w += (bytes + 255) & ~(size_t)255; return p;
    };
    u16* nh    = (u16*)alloc((size_t)ROWS*DIM*2);
    u16* whth  = (u16*)alloc((size_t)HID2*DIM*2);
    u16* wqkth = (u16*)alloc((size_t)QKD*DIM*2);
    u16* wqktl = (u16*)alloc((size_t)QKD*DIM*2);
    u16* woT   = (u16*)alloc((size_t)32*512*2);
    u16* q_f   = (u16*)alloc((size_t)ROWS*QKD*2);
    u16* k_f   = (u16*)alloc((size_t)ROWS*QKD*2);
    u16* v_f   = (u16*)alloc((size_t)BATCH*HID*SEQ*2);
    u16* gate_f= (u16*)alloc((size_t)ROWS*HID*2);       // bf16 C-frag layout
    float* part= (float*)alloc((size_t)2*ROWS*OUTD*4);

    prep_split<<<(HID2*DIM + QKD*DIM + 32*512)/256, 256, 0, stream>>>(Wh, Wqk, Wo, whth, wqkth, wqktl, woT);
    ln_kernel<<<ROWS/4, 256, 0, stream>>>(x, ln_g, ln_b, nh);
    gemm_h<<<2048, 256, 0, stream>>>(nh, whth, bh, v_f, gate_f);
    gemm_qk<<<ROWS/64, 256, 0, stream>>>(nh, wqkth, wqktl, bqk, gamma, beta, q_f, k_f);
    attn<<<512, 512, 0, stream>>>(q_f, k_f, v_f, gate_f, woT, part);
    reduce_out<<<ROWS*OUTD/1024, 256, 0, stream>>>(part, bo, out);
}

// Round 15
// 256.716 us; speedup vs baseline: 1.4468x; 1.0387x over previous
//
#include <hip/hip_runtime.h>
#include <stdint.h>

#define DIM   512
#define QKD   128
#define HID   1024
#define HID2  2048
#define OUTD  8
#define BATCH 4
#define SEQ   4096
#define ROWS  (BATCH*SEQ)   // 16384
#define LN_EPS 1e-5f

typedef unsigned short u16;
typedef unsigned int   u32;
typedef __bf16 bf16x8 __attribute__((ext_vector_type(8)));
typedef float  f32x4  __attribute__((ext_vector_type(4)));

// ---------- helpers ----------
__device__ inline u16 f2bf(float f){
    uint32_t u = __builtin_bit_cast(uint32_t, f);
    u += 0x7FFFu + ((u >> 16) & 1u);   // RNE
    return (u16)(u >> 16);
}
__device__ inline float bf2f(u16 h){
    uint32_t u = ((uint32_t)h) << 16;
    return __builtin_bit_cast(float, u);
}
__device__ inline void split_bf16(float x, u16 &hi, u16 &lo){
    hi = f2bf(x);
    float r = x - bf2f(hi);
    lo = f2bf(r);
}
__device__ inline bf16x8 ld_frag(const u16* p){
    uint4 r = *reinterpret_cast<const uint4*>(p);
    return __builtin_bit_cast(bf16x8, r);
}
__device__ inline f32x4 mfma16(bf16x8 a, bf16x8 b, f32x4 c){
    return __builtin_amdgcn_mfma_f32_16x16x32_bf16(a, b, c, 0, 0, 0);
}
__device__ inline float silu(float x){ return x / (1.f + expf(-x)); }
// async global->LDS: PER-LANE global src addr, wave-uniform LDS base (+lane*16B)
__device__ inline void gload_lds16(const u16* g, u16* l){
    __builtin_amdgcn_global_load_lds(
        (const __attribute__((address_space(1))) u32*)g,
        (__attribute__((address_space(3))) u32*)l, 16, 0, 0);
}

// ---------- P: quantize/transpose weights ----------
// Wh -> bf16 (transposed); Wqk -> split hi/lo (transposed);
// Wo -> bf16 B-frag-major WoT[32 chunks][512]: lane=(o&15)+16*(dl>>3), e=dl&7, o>=8 -> 0
__global__ void prep_split(const float* __restrict__ Wh, const float* __restrict__ Wqk,
                           const float* __restrict__ Wo,
                           u16* whth, u16* wqkth, u16* wqktl, u16* woT){
    int tid = blockIdx.x*256 + threadIdx.x;
    const int NWH = HID2*DIM;            // 1048576
    if (tid < NWH){
        int k = tid & (DIM-1);
        int n = tid >> 9;
        whth[tid] = f2bf(Wh[(size_t)k*HID2 + n]);
    } else if (tid < NWH + QKD*DIM){
        int t2 = tid - NWH;
        int k = t2 & (DIM-1);
        int n = t2 >> 9;
        float w = Wqk[(size_t)k*QKD + n];
        u16 h,l; split_bf16(w,h,l);
        wqkth[t2]=h; wqktl[t2]=l;
    } else {
        int t3 = tid - NWH - QKD*DIM;
        if (t3 < 32*512){
            int dt = t3 >> 9, l = (t3 >> 3) & 63, e = t3 & 7;
            int o  = l & 15, dl = ((l >> 4) << 3) + e;
            woT[t3] = (o < OUTD) ? f2bf(Wo[(size_t)(dt*32 + dl)*OUTD + o]) : (u16)0;
        }
    }
}

// ---------- K1: layernorm -> bf16 ----------
__global__ __launch_bounds__(256) void ln_kernel(const float* __restrict__ x,
                                                 const float* __restrict__ g,
                                                 const float* __restrict__ b,
                                                 u16* nh){
    int wave = threadIdx.x >> 6, lane = threadIdx.x & 63;
    int row  = blockIdx.x*4 + wave;
    const float* xr = x + (size_t)row*DIM;
    float4 v0 = *(const float4*)(xr + lane*8);
    float4 v1 = *(const float4*)(xr + lane*8 + 4);
    float xs[8] = {v0.x,v0.y,v0.z,v0.w,v1.x,v1.y,v1.z,v1.w};
    float s = 0.f, q = 0.f;
    #pragma unroll
    for (int i=0;i<8;++i){ s += xs[i]; q += xs[i]*xs[i]; }
    #pragma unroll
    for (int m=1;m<64;m<<=1){ s += __shfl_xor(s,m,64); q += __shfl_xor(q,m,64); }
    float mean = s * (1.f/DIM);
    float var  = q * (1.f/DIM) - mean*mean;
    float rstd = rsqrtf(var + LN_EPS);
    float4 g0 = *(const float4*)(g + lane*8);
    float4 g1 = *(const float4*)(g + lane*8 + 4);
    float4 b0 = *(const float4*)(b + lane*8);
    float4 b1 = *(const float4*)(b + lane*8 + 4);
    float gs[8] = {g0.x,g0.y,g0.z,g0.w,g1.x,g1.y,g1.z,g1.w};
    float bs[8] = {b0.x,b0.y,b0.z,b0.w,b1.x,b1.y,b1.z,b1.w};
    u16 hh[8];
    #pragma unroll
    for (int i=0;i<8;++i){
        float nv = (xs[i]-mean)*rstd*gs[i] + bs[i];
        hh[i] = f2bf(nv);
    }
    size_t o = (size_t)row*DIM + lane*8;
    *(uint4*)(nh + o) = *(uint4*)hh;
}

// ---------- K2: hidden = silu(bf16(n) @ bf16(Wh) + bh) -> v_f + gate_f (bf16 C-frags) ----------
// 128m x 256n tile, 512 threads / 8 waves (wave = 64x64 quadrant), m97 staging.
// grid 1024: nb = bid&7 (ONE n-panel per XCD, B L2-resident), mb = bid>>3.
__global__ __launch_bounds__(512,4) void gemm_h(
        const u16* __restrict__ nh,
        const u16* __restrict__ bth,
        const float* __restrict__ bh,
        u16* v_f, u16* gate_f){
    __shared__ __align__(16) u16 SH2[32768];   // SA 2x4096 | SB 2x8192 (48KB); VP overlay 64KB
    u16* SA = SH2;           // [2][4096]  128x32
    u16* SB = SH2 + 8192;    // [2][8192]  256x32
    const int bid = blockIdx.x;
    const int nb = bid & 7;              // 0..7, one per XCD
    const int mb = bid >> 3;             // 0..127
    const int n0 = nb*256, m0 = mb*128;
    const int w = threadIdx.x >> 6, lane = threadIdx.x & 63;
    const int wr = w >> 2, wc = w & 3;   // 2 x 4 quadrants of 64x64

    auto stage = [&](int ks, int p){
        {   // A: 128 rows, 1 KB per wave (16 rows)
            int row = w*16 + (lane>>2);
            gload_lds16(nh + (size_t)(m0+row)*DIM + ks*32 + (lane&3)*8,
                        &SA[p*4096 + w*512]);
        }
        #pragma unroll
        for (int c=0;c<2;++c){           // B: 256 rows, 2 KB per wave
            int row = w*32 + c*16 + (lane>>2);
            gload_lds16(bth + (size_t)(n0+row)*DIM + ks*32 + (lane&3)*8,
                        &SB[p*8192 + (w*2+c)*512]);
        }
    };

    stage(0, 0);
    __syncthreads();

    f32x4 acc[4][4] = {};
    for (int ks=0; ks<16; ++ks){
        const int p = ks & 1;
        if (ks < 15) stage(ks+1, p^1);
        bf16x8 Ah[4];
        #pragma unroll
        for (int rf=0;rf<4;++rf)
            Ah[rf] = ld_frag(&SA[p*4096 + (wr*64 + rf*16 + (lane&15))*32 + (lane>>4)*8]);
        #pragma unroll
        for (int cf=0;cf<4;++cf){
            bf16x8 Bh = ld_frag(&SB[p*8192 + (wc*64 + cf*16 + (lane&15))*32 + (lane>>4)*8]);
            #pragma unroll
            for (int rf=0;rf<4;++rf)
                acc[rf][cf] = mfma16(Ah[rf], Bh, acc[rf][cf]);
        }
        __syncthreads();
    }
    if (nb < 4){
        // v-path: frag-major 128x256 tile in LDS (64 frags x 512 u16 = 64 KB overlay),
        // then fully-coalesced 16B stores.
        u16* VP = SH2;
        #pragma unroll
        for (int rf=0;rf<4;++rf){
            #pragma unroll
            for (int cf=0;cf<4;++cf){
                #pragma unroll
                for (int r=0;r<4;++r){
                    int row_rel = wr*64 + rf*16 + (lane>>4)*4 + r;
                    int col_rel = wc*64 + cf*16 + (lane&15);
                    float s = silu(acc[rf][cf][r] + bh[n0 + col_rel]);
                    int f = ((row_rel>>5)<<4) | (col_rel>>4);
                    VP[f*512 + ((col_rel&15) + (((row_rel>>3)&3)<<4))*8 + (row_rel&7)] = f2bf(s);
                }
            }
        }
        __syncthreads();
        int fi = threadIdx.x >> 3, pt = threadIdx.x & 7;   // 64 frags x 8 threads
        int b  = m0 >> 12, itb = (m0 & 4095) >> 5;
        size_t gbase = (((size_t)b*128 + itb + (fi>>4))*64 + nb*16 + (fi&15))*512;
        #pragma unroll
        for (int c2=0;c2<8;++c2)
            *(uint4*)(v_f + gbase + pt*64 + c2*8) = *(uint4*)&VP[fi*512 + pt*64 + c2*8];
    } else {
        // gate-path: bf16 C-frag layout, coalesced uint2 per lane per frag.
        const int b  = m0 >> 12;
        const int i_rel = m0 & 4095;
        #pragma unroll
        for (int rf=0;rf<4;++rf){
            const int it = (i_rel + wr*64 + rf*16) >> 4;
            #pragma unroll
            for (int cf=0;cf<4;++cf){
                const int dt = ((nb-4)*256 + wc*64 + cf*16) >> 4;
                u16 gv[4];
                #pragma unroll
                for (int r=0;r<4;++r){
                    int col = n0 + wc*64 + cf*16 + (lane&15);
                    gv[r] = f2bf(silu(acc[rf][cf][r] + bh[col]));
                }
                size_t fo = (((size_t)b*256 + it)*64 + dt)*256 + lane*4;
                *(uint2*)(gate_f + fo) = *(uint2*)gv;
            }
        }
    }
}

// ---------- K3: Z = silu(bf16(n) @ (Wqk_hi+Wqk_lo) + bqk); q,k bf16 frag-major ----------
// m97 structure: gload_lds staging (A + B hi/lo), dbuf, 1 barrier/ks. M=64, grid 256.
__global__ __launch_bounds__(256,2) void gemm_qk(
        const u16* __restrict__ nh,
        const u16* __restrict__ bth, const u16* __restrict__ btl,
        const float* __restrict__ bqk, const float* __restrict__ gamma,
        const float* __restrict__ beta,
        u16* q_f, u16* k_f){
    __shared__ __align__(16) u16 SA [2][2048];   // 64 x 32
    __shared__ __align__(16) u16 SB0[2][4096];   // 128 x 32
    __shared__ __align__(16) u16 SB1[2][4096];
    int m0 = blockIdx.x * 64;
    int w = threadIdx.x >> 6, lane = threadIdx.x & 63;
    int wr = w >> 1, wc = w & 1;   // wave: 32q x 64n

    auto stage = [&](int ks, int p){
        {   // A: 64 rows, 1 chunk per wave
            int row = w*16 + (lane>>2);
            gload_lds16(nh + (size_t)(m0+row)*DIM + ks*32 + (lane&3)*8, &SA[p][w*512]);
        }
        #pragma unroll
        for (int c=0;c<2;++c){
            int row = w*32 + c*16 + (lane>>2);   // 0..127
            int off = w*1024 + c*512;
            gload_lds16(bth + (size_t)row*DIM + ks*32 + (lane&3)*8, &SB0[p][off]);
            gload_lds16(btl + (size_t)row*DIM + ks*32 + (lane&3)*8, &SB1[p][off]);
        }
    };

    stage(0, 0);
    __syncthreads();

    f32x4 acc[2][4] = {};
    for (int ks=0; ks<16; ++ks){
        const int p = ks & 1;
        if (ks < 15) stage(ks+1, p^1);
        bf16x8 Ah[2];
        #pragma unroll
        for (int rf=0;rf<2;++rf)
            Ah[rf] = ld_frag(&SA[p][(wr*32 + rf*16 + (lane&15))*32 + (lane>>4)*8]);
        #pragma unroll
        for (int cf=0;cf<4;++cf){
            bf16x8 Bh = ld_frag(&SB0[p][(wc*64 + cf*16 + (lane&15))*32 + (lane>>4)*8]);
            bf16x8 Bl = ld_frag(&SB1[p][(wc*64 + cf*16 + (lane&15))*32 + (lane>>4)*8]);
            #pragma unroll
            for (int rf=0;rf<2;++rf){
                acc[rf][cf] = mfma16(Ah[rf], Bh, acc[rf][cf]);
                acc[rf][cf] = mfma16(Ah[rf], Bl, acc[rf][cf]);
            }
        }
        __syncthreads();
    }
    #pragma unroll
    for (int rf=0;rf<2;++rf){
        #pragma unroll
        for (int cf=0;cf<4;++cf){
            #pragma unroll
            for (int r=0;r<4;++r){
                int row = m0 + wr*32 + rf*16 + (lane>>4)*4 + r;
                int col = wc*64 + cf*16 + (lane&15);
                float z = silu(acc[rf][cf][r] + bqk[col]);
                float qv = z*gamma[col]       + beta[col];
                float kv = z*gamma[QKD + col] + beta[QKD + col];
                size_t lane_e = (size_t)((row&15) + (((col>>3)&3)<<4))*8 + (col&7);
                size_t it4ks  = (size_t)(row>>4)*4 + (col>>5);
                q_f[it4ks*512 + lane_e] = f2bf(qv);
                k_f[it4ks*512 + lane_e] = f2bf(kv);
            }
        }
    }
}

// ---------- K4: fused squared-relu attention + Wo projection ----------
// Main loop IDENTICAL to round-9/11/13/14 (known-good). Epilogue: Vg=acc*gate*2^-24
// (gate read as bf16 C-frags, coalesced) -> bf16 frag-major LDS -> 16 MFMA vs WoT
// -> per-block out-partials.
__global__ __launch_bounds__(512,4) void attn(
        const u16* __restrict__ q_f, const u16* __restrict__ k_f,
        const u16* __restrict__ v_f, const u16* __restrict__ gate_f,
        const u16* __restrict__ woT, float* part){
    __shared__ __align__(16) u16 SH[33792];   // QL 8192 | KT 2x8192 | AT 2x4608
    u16* QL = SH;
    u16* KT0 = SH + 8192;
    u16* AT0 = SH + 24576;
    const int bid = blockIdx.x, xcd = bid & 7;
    const int batch = xcd >> 1, dhalf = xcd & 1, qt = bid >> 3;
    const int i0 = qt * 64;
    const int w = threadIdx.x >> 6, lane = threadIdx.x & 63;
    const int fr = w >> 1, fc = w & 1;    // QK: 16q strip x 32j half
    const int ds = w;                     // PV: 64d slice

    // ---- stage Q once + K(0), async ----
    {
        size_t qbase = ((size_t)(batch*256 + qt*4))*2048;
        size_t kbase = ((size_t)(batch*256 + 0*4))*2048;
        #pragma unroll
        for (int c=0;c<2;++c){
            int off = w*1024 + c*512;
            gload_lds16(q_f + qbase + off + lane*8, &QL[off]);
            gload_lds16(k_f + kbase + off + lane*8, &KT0[off]);
        }
    }
    __syncthreads();

    f32x4 acc[4][4] = {};   // 64q x 64d per wave
    for (int kt=0; kt<64; ++kt){
        const int p = kt & 1;
        {
            size_t kbase = ((size_t)(batch*256 + (((kt+1)&63))*4))*2048;
            #pragma unroll
            for (int c=0;c<2;++c){
                int off = w*1024 + c*512;
                gload_lds16(k_f + kbase + off + lane*8, &KT0[(p^1)*8192 + off]);
            }
        }
        bf16x8 vb0[4];
        #pragma unroll
        for (int dc=0;dc<4;++dc)
            vb0[dc] = ld_frag(v_f + (((size_t)(batch*128 + kt*2))*64
                              + dhalf*32 + ds*4 + dc)*512 + lane*8);
        f32x4 sacc[2] = {};
        #pragma unroll
        for (int ks=0;ks<4;++ks){
            bf16x8 qa = ld_frag(&QL[fr*2048 + ks*512 + lane*8]);
            #pragma unroll
            for (int t=0;t<2;++t){
                bf16x8 kb = ld_frag(&KT0[p*8192 + (fc*2 + t)*2048 + ks*512 + lane*8]);
                sacc[t] = mfma16(qa, kb, sacc[t]);
            }
        }
        u16* Ab = AT0 + p*4608;
        #pragma unroll
        for (int t=0;t<2;++t){
            #pragma unroll
            for (int r=0;r<4;++r){
                float s = sacc[t][r];
                s = s > 0.f ? s*s : 0.f;
                int q = fr*16 + (lane>>4)*4 + r;
                int j = fc*32 + t*16 + (lane&15);
                Ab[q*72 + j] = f2bf(s);
            }
        }
        __syncthreads();
        #pragma unroll
        for (int qr=0;qr<4;++qr){
            bf16x8 af = ld_frag(&Ab[(qr*16 + (lane&15))*72 + (lane>>4)*8]);
            #pragma unroll
            for (int dc=0;dc<4;++dc)
                acc[qr][dc] = mfma16(af, vb0[dc], acc[qr][dc]);
        }
        bf16x8 vb1[4];
        #pragma unroll
        for (int dc=0;dc<4;++dc)
            vb1[dc] = ld_frag(v_f + (((size_t)(batch*128 + kt*2 + 1))*64
                              + dhalf*32 + ds*4 + dc)*512 + lane*8);
        #pragma unroll
        for (int qr=0;qr<4;++qr){
            bf16x8 af = ld_frag(&Ab[(qr*16 + (lane&15))*72 + 32 + (lane>>4)*8]);
            #pragma unroll
            for (int dc=0;dc<4;++dc)
                acc[qr][dc] = mfma16(af, vb1[dc], acc[qr][dc]);
        }
    }
    // ---- epilogue: Vg = acc*gate*2^-24 -> LDS (A-frag layout) -> @ WoT -> part ----
    __syncthreads();   // done with QL/KT/AT reads; overlay VgL
    u16* VgL = SH;     // 16 dchunks x 4 qtiles x 512 u16 = 64 KB
    #pragma unroll
    for (int qr=0; qr<4; ++qr){
        #pragma unroll
        for (int dc=0; dc<4; ++dc){
            // gate C-frag: it = qt*4+qr, dt = dhalf*32 + ds*4 + dc
            size_t fo = (((size_t)batch*256 + qt*4 + qr)*64 + dhalf*32 + ds*4 + dc)*256 + lane*4;
            uint2 gvp = *(const uint2*)(gate_f + fo);
            u16* gv = (u16*)&gvp;
            #pragma unroll
            for (int r=0; r<4; ++r){
                int d_local = ds*64 + dc*16 + (lane&15);
                float vg = acc[qr][dc][r] * bf2f(gv[r]) * 0x1p-24f;
                int dchunk = (d_local >> 5);
                int dl = d_local & 31;
                int q16 = (lane>>4)*4 + r;
                VgL[(dchunk*4 + qr)*512 + (q16 + ((dl>>3)<<4))*8 + (dl&7)] = f2bf(vg);
            }
        }
    }
    __syncthreads();
    if (w < 4){
        f32x4 oc = {};
        #pragma unroll
        for (int ch=0; ch<16; ++ch){
            bf16x8 a = ld_frag(&VgL[(ch*4 + w)*512 + lane*8]);
            bf16x8 b = ld_frag(woT + ((size_t)(dhalf*16 + ch))*512 + lane*8);
            oc = mfma16(a, b, oc);
        }
        if ((lane & 15) < OUTD){
            size_t base = ((size_t)dhalf*ROWS + batch*SEQ + i0 + w*16)*OUTD;
            #pragma unroll
            for (int r=0;r<4;++r)
                part[base + (size_t)((lane>>4)*4 + r)*OUTD + (lane&15)] = oc[r];
        }
    }
}

// ---------- K5: out = part0 + part1 + bo ----------
__global__ __launch_bounds__(256) void reduce_out(const float* __restrict__ part,
                                                  const float* __restrict__ bo,
                                                  float* __restrict__ out){
    int idx = (blockIdx.x*256 + threadIdx.x)*4;   // ROWS*8 = 131072 floats
    float4 a = *(const float4*)(part + idx);
    float4 b = *(const float4*)(part + (size_t)ROWS*OUTD + idx);
    float4 c = *(const float4*)(bo + (idx & 7));
    float4 o = {a.x+b.x+c.x, a.y+b.y+c.y, a.z+b.z+c.z, a.w+b.w+c.w};
    *(float4*)(out + idx) = o;
}

// ---------- launch ----------
extern "C" void kernel_launch(void* const* d_in, const int* in_sizes, int n_in,
                              void* d_out, int out_size, void* d_ws, size_t ws_size,
                              hipStream_t stream){
    const float* x    = (const float*)d_in[0];
    const float* ln_g = (const float*)d_in[1];
    const float* ln_b = (const float*)d_in[2];
    const float* Wh   = (const float*)d_in[3];
    const float* bh   = (const float*)d_in[4];
    const float* Wqk  = (const float*)d_in[5];
    const float* bqk  = (const float*)d_in[6];
    const float* gamma= (const float*)d_in[7];
    const float* beta = (const float*)d_in[8];
    const float* Wo   = (const float*)d_in[9];
    const float* bo   = (const float*)d_in[10];
    float* out = (float*)d_out;

    char* w = (char*)d_ws;
    auto alloc = [&](size_t bytes)->char*{
        char* p = w; w += (bytes + 255) & ~(size_t)255; return p;
    };
    u16* nh    = (u16*)alloc((size_t)ROWS*DIM*2);
    u16* whth  = (u16*)alloc((size_t)HID2*DIM*2);
    u16* wqkth = (u16*)alloc((size_t)QKD*DIM*2);
    u16* wqktl = (u16*)alloc((size_t)QKD*DIM*2);
    u16* woT   = (u16*)alloc((size_t)32*512*2);
    u16* q_f   = (u16*)alloc((size_t)ROWS*QKD*2);
    u16* k_f   = (u16*)alloc((size_t)ROWS*QKD*2);
    u16* v_f   = (u16*)alloc((size_t)BATCH*HID*SEQ*2);
    u16* gate_f= (u16*)alloc((size_t)ROWS*HID*2);       // bf16 C-frag layout
    float* part= (float*)alloc((size_t)2*ROWS*OUTD*4);

    prep_split<<<(HID2*DIM + QKD*DIM + 32*512)/256, 256, 0, stream>>>(Wh, Wqk, Wo, whth, wqkth, wqktl, woT);
    ln_kernel<<<ROWS/4, 256, 0, stream>>>(x, ln_g, ln_b, nh);
    gemm_h<<<1024, 512, 0, stream>>>(nh, whth, bh, v_f, gate_f);
    gemm_qk<<<ROWS/64, 256, 0, stream>>>(nh, wqkth, wqktl, bqk, gamma, beta, q_f, k_f);
    attn<<<512, 512, 0, stream>>>(q_f, k_f, v_f, gate_f, woT, part);
    reduce_out<<<ROWS*OUTD/1024, 256, 0, stream>>>(part, bo, out);
}

// Round 16
// 248.558 us; speedup vs baseline: 1.4943x; 1.0328x over previous
//
#include <hip/hip_runtime.h>
#include <stdint.h>

#define DIM   512
#define QKD   128
#define HID   1024
#define HID2  2048
#define OUTD  8
#define BATCH 4
#define SEQ   4096
#define ROWS  (BATCH*SEQ)   // 16384
#define LN_EPS 1e-5f

typedef unsigned short u16;
typedef unsigned int   u32;
typedef __bf16 bf16x8 __attribute__((ext_vector_type(8)));
typedef float  f32x4  __attribute__((ext_vector_type(4)));

// ---------- helpers ----------
__device__ inline u16 f2bf(float f){
    uint32_t u = __builtin_bit_cast(uint32_t, f);
    u += 0x7FFFu + ((u >> 16) & 1u);   // RNE
    return (u16)(u >> 16);
}
__device__ inline float bf2f(u16 h){
    uint32_t u = ((uint32_t)h) << 16;
    return __builtin_bit_cast(float, u);
}
__device__ inline void split_bf16(float x, u16 &hi, u16 &lo){
    hi = f2bf(x);
    float r = x - bf2f(hi);
    lo = f2bf(r);
}
__device__ inline bf16x8 ld_frag(const u16* p){
    uint4 r = *reinterpret_cast<const uint4*>(p);
    return __builtin_bit_cast(bf16x8, r);
}
__device__ inline f32x4 mfma16(bf16x8 a, bf16x8 b, f32x4 c){
    return __builtin_amdgcn_mfma_f32_16x16x32_bf16(a, b, c, 0, 0, 0);
}
__device__ inline float silu(float x){ return x / (1.f + expf(-x)); }
// async global->LDS: PER-LANE global src addr, wave-uniform LDS base (+lane*16B)
__device__ inline void gload_lds16(const u16* g, u16* l){
    __builtin_amdgcn_global_load_lds(
        (const __attribute__((address_space(1))) u32*)g,
        (__attribute__((address_space(3))) u32*)l, 16, 0, 0);
}

// ---------- K1: fused layernorm + weight prep ----------
// bid < 4096: LN rows -> bf16.  bid >= 4096: quantize/transpose Wh, Wqk, Wo.
__global__ __launch_bounds__(256) void pre_kernel(
        const float* __restrict__ x, const float* __restrict__ g,
        const float* __restrict__ b, u16* nh,
        const float* __restrict__ Wh, const float* __restrict__ Wqk,
        const float* __restrict__ Wo,
        u16* whth, u16* wqkth, u16* wqktl, u16* woT){
    if (blockIdx.x < 4096){
        int wave = threadIdx.x >> 6, lane = threadIdx.x & 63;
        int row  = blockIdx.x*4 + wave;
        const float* xr = x + (size_t)row*DIM;
        float4 v0 = *(const float4*)(xr + lane*8);
        float4 v1 = *(const float4*)(xr + lane*8 + 4);
        float xs[8] = {v0.x,v0.y,v0.z,v0.w,v1.x,v1.y,v1.z,v1.w};
        float s = 0.f, q = 0.f;
        #pragma unroll
        for (int i=0;i<8;++i){ s += xs[i]; q += xs[i]*xs[i]; }
        #pragma unroll
        for (int m=1;m<64;m<<=1){ s += __shfl_xor(s,m,64); q += __shfl_xor(q,m,64); }
        float mean = s * (1.f/DIM);
        float var  = q * (1.f/DIM) - mean*mean;
        float rstd = rsqrtf(var + LN_EPS);
        float4 g0 = *(const float4*)(g + lane*8);
        float4 g1 = *(const float4*)(g + lane*8 + 4);
        float4 b0 = *(const float4*)(b + lane*8);
        float4 b1 = *(const float4*)(b + lane*8 + 4);
        float gs[8] = {g0.x,g0.y,g0.z,g0.w,g1.x,g1.y,g1.z,g1.w};
        float bs[8] = {b0.x,b0.y,b0.z,b0.w,b1.x,b1.y,b1.z,b1.w};
        u16 hh[8];
        #pragma unroll
        for (int i=0;i<8;++i){
            float nv = (xs[i]-mean)*rstd*gs[i] + bs[i];
            hh[i] = f2bf(nv);
        }
        size_t o = (size_t)row*DIM + lane*8;
        *(uint4*)(nh + o) = *(uint4*)hh;
    } else {
        int tid = (blockIdx.x - 4096)*256 + threadIdx.x;
        const int NWH = HID2*DIM;            // 1048576
        if (tid < NWH){
            int k = tid & (DIM-1);
            int n = tid >> 9;
            whth[tid] = f2bf(Wh[(size_t)k*HID2 + n]);
        } else if (tid < NWH + QKD*DIM){
            int t2 = tid - NWH;
            int k = t2 & (DIM-1);
            int n = t2 >> 9;
            float w = Wqk[(size_t)k*QKD + n];
            u16 h,l; split_bf16(w,h,l);
            wqkth[t2]=h; wqktl[t2]=l;
        } else {
            int t3 = tid - NWH - QKD*DIM;
            if (t3 < 32*512){
                int dt = t3 >> 9, l = (t3 >> 3) & 63, e = t3 & 7;
                int o  = l & 15, dl = ((l >> 4) << 3) + e;
                woT[t3] = (o < OUTD) ? f2bf(Wo[(size_t)(dt*32 + dl)*OUTD + o]) : (u16)0;
            }
        }
    }
}

// ---------- K2: fused GEMMs ----------
// bid < 1024: h-role  = silu(bf16(n) @ bf16(Wh) + bh) -> v_f + gate_f (C-frags).
//             128m x 256n, 8 waves (64x64 quadrants), nb = bid&7 (1 n-panel/XCD).
// bid >= 1024: qk-role = silu(bf16(n) @ (Wqk_hi+Wqk_lo) + bqk) -> q_f, k_f.
//             128m x 128n, 8 waves (32q x 64n), m97 staging.
__global__ __launch_bounds__(512,4) void gemm_fused(
        const u16* __restrict__ nh,
        const u16* __restrict__ whT, const float* __restrict__ bh,
        u16* v_f, u16* gate_f,
        const u16* __restrict__ qkh, const u16* __restrict__ qkl,
        const float* __restrict__ bqk, const float* __restrict__ gamma,
        const float* __restrict__ beta,
        u16* q_f, u16* k_f){
    __shared__ __align__(16) u16 SH2[32768];
    const int w = threadIdx.x >> 6, lane = threadIdx.x & 63;
    if (blockIdx.x < 1024){
        // ================= h role =================
        u16* SA = SH2;           // [2][4096]  128x32
        u16* SB = SH2 + 8192;    // [2][8192]  256x32
        const int bid = blockIdx.x;
        const int nb = bid & 7;              // 0..7, one per XCD
        const int mb = bid >> 3;             // 0..127
        const int n0 = nb*256, m0 = mb*128;
        const int wr = w >> 2, wc = w & 3;   // 2 x 4 quadrants of 64x64

        auto stage = [&](int ks, int p){
            {   // A: 128 rows, 1 KB per wave (16 rows)
                int row = w*16 + (lane>>2);
                gload_lds16(nh + (size_t)(m0+row)*DIM + ks*32 + (lane&3)*8,
                            &SA[p*4096 + w*512]);
            }
            #pragma unroll
            for (int c=0;c<2;++c){           // B: 256 rows, 2 KB per wave
                int row = w*32 + c*16 + (lane>>2);
                gload_lds16(whT + (size_t)(n0+row)*DIM + ks*32 + (lane&3)*8,
                            &SB[p*8192 + (w*2+c)*512]);
            }
        };

        stage(0, 0);
        __syncthreads();

        f32x4 acc[4][4] = {};
        for (int ks=0; ks<16; ++ks){
            const int p = ks & 1;
            if (ks < 15) stage(ks+1, p^1);
            bf16x8 Ah[4];
            #pragma unroll
            for (int rf=0;rf<4;++rf)
                Ah[rf] = ld_frag(&SA[p*4096 + (wr*64 + rf*16 + (lane&15))*32 + (lane>>4)*8]);
            #pragma unroll
            for (int cf=0;cf<4;++cf){
                bf16x8 Bh = ld_frag(&SB[p*8192 + (wc*64 + cf*16 + (lane&15))*32 + (lane>>4)*8]);
                #pragma unroll
                for (int rf=0;rf<4;++rf)
                    acc[rf][cf] = mfma16(Ah[rf], Bh, acc[rf][cf]);
            }
            __syncthreads();
        }
        if (nb < 4){
            // v-path: frag-major 128x256 tile in LDS (64 frags, 64 KB overlay),
            // then fully-coalesced 16B stores.
            u16* VP = SH2;
            #pragma unroll
            for (int rf=0;rf<4;++rf){
                #pragma unroll
                for (int cf=0;cf<4;++cf){
                    #pragma unroll
                    for (int r=0;r<4;++r){
                        int row_rel = wr*64 + rf*16 + (lane>>4)*4 + r;
                        int col_rel = wc*64 + cf*16 + (lane&15);
                        float s = silu(acc[rf][cf][r] + bh[n0 + col_rel]);
                        int f = ((row_rel>>5)<<4) | (col_rel>>4);
                        VP[f*512 + ((col_rel&15) + (((row_rel>>3)&3)<<4))*8 + (row_rel&7)] = f2bf(s);
                    }
                }
            }
            __syncthreads();
            int fi = threadIdx.x >> 3, pt = threadIdx.x & 7;   // 64 frags x 8 threads
            int b  = m0 >> 12, itb = (m0 & 4095) >> 5;
            size_t gbase = (((size_t)b*128 + itb + (fi>>4))*64 + nb*16 + (fi&15))*512;
            #pragma unroll
            for (int c2=0;c2<8;++c2)
                *(uint4*)(v_f + gbase + pt*64 + c2*8) = *(uint4*)&VP[fi*512 + pt*64 + c2*8];
        } else {
            // gate-path: bf16 C-frag layout, coalesced uint2 per lane per frag.
            const int b  = m0 >> 12;
            const int i_rel = m0 & 4095;
            #pragma unroll
            for (int rf=0;rf<4;++rf){
                const int it = (i_rel + wr*64 + rf*16) >> 4;
                #pragma unroll
                for (int cf=0;cf<4;++cf){
                    const int dt = ((nb-4)*256 + wc*64 + cf*16) >> 4;
                    u16 gv[4];
                    #pragma unroll
                    for (int r=0;r<4;++r){
                        int col = n0 + wc*64 + cf*16 + (lane&15);
                        gv[r] = f2bf(silu(acc[rf][cf][r] + bh[col]));
                    }
                    size_t fo = (((size_t)b*256 + it)*64 + dt)*256 + lane*4;
                    *(uint2*)(gate_f + fo) = *(uint2*)gv;
                }
            }
        }
    } else {
        // ================= qk role =================
        u16* SA  = SH2;            // [2][4096]  128x32
        u16* SB0 = SH2 + 8192;     // [2][4096]  128x32
        u16* SB1 = SH2 + 16384;    // [2][4096]
        const int m0 = (blockIdx.x - 1024) * 128;
        const int wr = w >> 1, wc = w & 1;   // wave: 32q x 64n (8 waves = 128q x 128n)

        auto stage = [&](int ks, int p){
            int row = w*16 + (lane>>2);      // 16 rows per wave
            gload_lds16(nh  + (size_t)(m0+row)*DIM + ks*32 + (lane&3)*8, &SA [p*4096 + w*512]);
            gload_lds16(qkh + (size_t)row*DIM      + ks*32 + (lane&3)*8, &SB0[p*4096 + w*512]);
            gload_lds16(qkl + (size_t)row*DIM      + ks*32 + (lane&3)*8, &SB1[p*4096 + w*512]);
        };

        stage(0, 0);
        __syncthreads();

        f32x4 acc[2][4] = {};
        for (int ks=0; ks<16; ++ks){
            const int p = ks & 1;
            if (ks < 15) stage(ks+1, p^1);
            bf16x8 Ah[2];
            #pragma unroll
            for (int rf=0;rf<2;++rf)
                Ah[rf] = ld_frag(&SA[p*4096 + (wr*32 + rf*16 + (lane&15))*32 + (lane>>4)*8]);
            #pragma unroll
            for (int cf=0;cf<4;++cf){
                bf16x8 Bh = ld_frag(&SB0[p*4096 + (wc*64 + cf*16 + (lane&15))*32 + (lane>>4)*8]);
                bf16x8 Bl = ld_frag(&SB1[p*4096 + (wc*64 + cf*16 + (lane&15))*32 + (lane>>4)*8]);
                #pragma unroll
                for (int rf=0;rf<2;++rf){
                    acc[rf][cf] = mfma16(Ah[rf], Bh, acc[rf][cf]);
                    acc[rf][cf] = mfma16(Ah[rf], Bl, acc[rf][cf]);
                }
            }
            __syncthreads();
        }
        #pragma unroll
        for (int rf=0;rf<2;++rf){
            #pragma unroll
            for (int cf=0;cf<4;++cf){
                #pragma unroll
                for (int r=0;r<4;++r){
                    int row = m0 + wr*32 + rf*16 + (lane>>4)*4 + r;
                    int col = wc*64 + cf*16 + (lane&15);
                    float z = silu(acc[rf][cf][r] + bqk[col]);
                    float qv = z*gamma[col]       + beta[col];
                    float kv = z*gamma[QKD + col] + beta[QKD + col];
                    size_t lane_e = (size_t)((row&15) + (((col>>3)&3)<<4))*8 + (col&7);
                    size_t it4ks  = (size_t)(row>>4)*4 + (col>>5);
                    q_f[it4ks*512 + lane_e] = f2bf(qv);
                    k_f[it4ks*512 + lane_e] = f2bf(kv);
                }
            }
        }
    }
}

// ---------- K3: fused squared-relu attention + Wo projection ----------
// Main loop IDENTICAL to round-9..15 (known-good). Epilogue: Vg=acc*gate*2^-24
// (gate read as bf16 C-frags, coalesced) -> bf16 frag-major LDS -> 16 MFMA vs WoT
// -> per-block out-partials.
__global__ __launch_bounds__(512,4) void attn(
        const u16* __restrict__ q_f, const u16* __restrict__ k_f,
        const u16* __restrict__ v_f, const u16* __restrict__ gate_f,
        const u16* __restrict__ woT, float* part){
    __shared__ __align__(16) u16 SH[33792];   // QL 8192 | KT 2x8192 | AT 2x4608
    u16* QL = SH;
    u16* KT0 = SH + 8192;
    u16* AT0 = SH + 24576;
    const int bid = blockIdx.x, xcd = bid & 7;
    const int batch = xcd >> 1, dhalf = xcd & 1, qt = bid >> 3;
    const int i0 = qt * 64;
    const int w = threadIdx.x >> 6, lane = threadIdx.x & 63;
    const int fr = w >> 1, fc = w & 1;    // QK: 16q strip x 32j half
    const int ds = w;                     // PV: 64d slice

    // ---- stage Q once + K(0), async ----
    {
        size_t qbase = ((size_t)(batch*256 + qt*4))*2048;
        size_t kbase = ((size_t)(batch*256 + 0*4))*2048;
        #pragma unroll
        for (int c=0;c<2;++c){
            int off = w*1024 + c*512;
            gload_lds16(q_f + qbase + off + lane*8, &QL[off]);
            gload_lds16(k_f + kbase + off + lane*8, &KT0[off]);
        }
    }
    __syncthreads();

    f32x4 acc[4][4] = {};   // 64q x 64d per wave
    for (int kt=0; kt<64; ++kt){
        const int p = kt & 1;
        {
            size_t kbase = ((size_t)(batch*256 + (((kt+1)&63))*4))*2048;
            #pragma unroll
            for (int c=0;c<2;++c){
                int off = w*1024 + c*512;
                gload_lds16(k_f + kbase + off + lane*8, &KT0[(p^1)*8192 + off]);
            }
        }
        bf16x8 vb0[4];
        #pragma unroll
        for (int dc=0;dc<4;++dc)
            vb0[dc] = ld_frag(v_f + (((size_t)(batch*128 + kt*2))*64
                              + dhalf*32 + ds*4 + dc)*512 + lane*8);
        f32x4 sacc[2] = {};
        #pragma unroll
        for (int ks=0;ks<4;++ks){
            bf16x8 qa = ld_frag(&QL[fr*2048 + ks*512 + lane*8]);
            #pragma unroll
            for (int t=0;t<2;++t){
                bf16x8 kb = ld_frag(&KT0[p*8192 + (fc*2 + t)*2048 + ks*512 + lane*8]);
                sacc[t] = mfma16(qa, kb, sacc[t]);
            }
        }
        u16* Ab = AT0 + p*4608;
        #pragma unroll
        for (int t=0;t<2;++t){
            #pragma unroll
            for (int r=0;r<4;++r){
                float s = sacc[t][r];
                s = s > 0.f ? s*s : 0.f;
                int q = fr*16 + (lane>>4)*4 + r;
                int j = fc*32 + t*16 + (lane&15);
                Ab[q*72 + j] = f2bf(s);
            }
        }
        __syncthreads();
        #pragma unroll
        for (int qr=0;qr<4;++qr){
            bf16x8 af = ld_frag(&Ab[(qr*16 + (lane&15))*72 + (lane>>4)*8]);
            #pragma unroll
            for (int dc=0;dc<4;++dc)
                acc[qr][dc] = mfma16(af, vb0[dc], acc[qr][dc]);
        }
        bf16x8 vb1[4];
        #pragma unroll
        for (int dc=0;dc<4;++dc)
            vb1[dc] = ld_frag(v_f + (((size_t)(batch*128 + kt*2 + 1))*64
                              + dhalf*32 + ds*4 + dc)*512 + lane*8);
        #pragma unroll
        for (int qr=0;qr<4;++qr){
            bf16x8 af = ld_frag(&Ab[(qr*16 + (lane&15))*72 + 32 + (lane>>4)*8]);
            #pragma unroll
            for (int dc=0;dc<4;++dc)
                acc[qr][dc] = mfma16(af, vb1[dc], acc[qr][dc]);
        }
    }
    // ---- epilogue: Vg = acc*gate*2^-24 -> LDS (A-frag layout) -> @ WoT -> part ----
    __syncthreads();   // done with QL/KT/AT reads; overlay VgL
    u16* VgL = SH;     // 16 dchunks x 4 qtiles x 512 u16 = 64 KB
    #pragma unroll
    for (int qr=0; qr<4; ++qr){
        #pragma unroll
        for (int dc=0; dc<4; ++dc){
            // gate C-frag: it = qt*4+qr, dt = dhalf*32 + ds*4 + dc
            size_t fo = (((size_t)batch*256 + qt*4 + qr)*64 + dhalf*32 + ds*4 + dc)*256 + lane*4;
            uint2 gvp = *(const uint2*)(gate_f + fo);
            u16* gv = (u16*)&gvp;
            #pragma unroll
            for (int r=0; r<4; ++r){
                int d_local = ds*64 + dc*16 + (lane&15);
                float vg = acc[qr][dc][r] * bf2f(gv[r]) * 0x1p-24f;
                int dchunk = (d_local >> 5);
                int dl = d_local & 31;
                int q16 = (lane>>4)*4 + r;
                VgL[(dchunk*4 + qr)*512 + (q16 + ((dl>>3)<<4))*8 + (dl&7)] = f2bf(vg);
            }
        }
    }
    __syncthreads();
    if (w < 4){
        f32x4 oc = {};
        #pragma unroll
        for (int ch=0; ch<16; ++ch){
            bf16x8 a = ld_frag(&VgL[(ch*4 + w)*512 + lane*8]);
            bf16x8 b = ld_frag(woT + ((size_t)(dhalf*16 + ch))*512 + lane*8);
            oc = mfma16(a, b, oc);
        }
        if ((lane & 15) < OUTD){
            size_t base = ((size_t)dhalf*ROWS + batch*SEQ + i0 + w*16)*OUTD;
            #pragma unroll
            for (int r=0;r<4;++r)
                part[base + (size_t)((lane>>4)*4 + r)*OUTD + (lane&15)] = oc[r];
        }
    }
}

// ---------- K4: out = part0 + part1 + bo ----------
__global__ __launch_bounds__(256) void reduce_out(const float* __restrict__ part,
                                                  const float* __restrict__ bo,
                                                  float* __restrict__ out){
    int idx = (blockIdx.x*256 + threadIdx.x)*4;   // ROWS*8 = 131072 floats
    float4 a = *(const float4*)(part + idx);
    float4 b = *(const float4*)(part + (size_t)ROWS*OUTD + idx);
    float4 c = *(const float4*)(bo + (idx & 7));
    float4 o = {a.x+b.x+c.x, a.y+b.y+c.y, a.z+b.z+c.z, a.w+b.w+c.w};
    *(float4*)(out + idx) = o;
}

// ---------- launch ----------
extern "C" void kernel_launch(void* const* d_in, const int* in_sizes, int n_in,
                              void* d_out, int out_size, void* d_ws, size_t ws_size,
                              hipStream_t stream){
    const float* x    = (const float*)d_in[0];
    const float* ln_g = (const float*)d_in[1];
    const float* ln_b = (const float*)d_in[2];
    const float* Wh   = (const float*)d_in[3];
    const float* bh   = (const float*)d_in[4];
    const float* Wqk  = (const float*)d_in[5];
    const float* bqk  = (const float*)d_in[6];
    const float* gamma= (const float*)d_in[7];
    const float* beta = (const float*)d_in[8];
    const float* Wo   = (const float*)d_in[9];
    const float* bo   = (const float*)d_in[10];
    float* out = (float*)d_out;

    char* w = (char*)d_ws;
    auto alloc = [&](size_t bytes)->char*{
        char* p = w; w += (bytes + 255) & ~(size_t)255; return p;
    };
    u16* nh    = (u16*)alloc((size_t)ROWS*DIM*2);
    u16* whth  = (u16*)alloc((size_t)HID2*DIM*2);
    u16* wqkth = (u16*)alloc((size_t)QKD*DIM*2);
    u16* wqktl = (u16*)alloc((size_t)QKD*DIM*2);
    u16* woT   = (u16*)alloc((size_t)32*512*2);
    u16* q_f   = (u16*)alloc((size_t)ROWS*QKD*2);
    u16* k_f   = (u16*)alloc((size_t)ROWS*QKD*2);
    u16* v_f   = (u16*)alloc((size_t)BATCH*HID*SEQ*2);
    u16* gate_f= (u16*)alloc((size_t)ROWS*HID*2);       // bf16 C-frag layout
    float* part= (float*)alloc((size_t)2*ROWS*OUTD*4);

    const int PREP_BLOCKS = (HID2*DIM + QKD*DIM + 32*512)/256;   // 4416
    pre_kernel<<<4096 + PREP_BLOCKS, 256, 0, stream>>>(
        x, ln_g, ln_b, nh, Wh, Wqk, Wo, whth, wqkth, wqktl, woT);
    gemm_fused<<<1024 + ROWS/128, 512, 0, stream>>>(
        nh, whth, bh, v_f, gate_f, wqkth, wqktl, bqk, gamma, beta, q_f, k_f);
    attn<<<512, 512, 0, stream>>>(q_f, k_f, v_f, gate_f, woT, part);
    reduce_out<<<ROWS*OUTD/1024, 256, 0, stream>>>(part, bo, out);
}